// Round 2
// baseline (570.875 us; speedup 1.0000x reference)
//
#include <hip/hip_runtime.h>

// Problem constants (B=8, L=1024, D=1024, H=16, DH=64)
#define B_  8
#define L_  1024
#define D_  1024
#define H_  16
#define DH_ 64

typedef unsigned short u16;
typedef __attribute__((ext_vector_type(8))) short short8;   // 8 x bf16 (4 VGPRs)
typedef __attribute__((ext_vector_type(4))) float floatx4;  // MFMA 16x16 C/D frag

// fp32 -> bf16 round-to-nearest-even
static __device__ __forceinline__ u16 f2bf(float f) {
  union { float f; unsigned u; } cv; cv.f = f;
  unsigned u = cv.u;
  return (u16)((u + 0x7fffu + ((u >> 16) & 1u)) >> 16);
}
static __device__ __forceinline__ float bf2f(u16 h) {
  union { unsigned u; float f; } cv; cv.u = ((unsigned)h) << 16;
  return cv.f;
}

// ---------------------------------------------------------------- split f32 -> (hi, lo) bf16
// x ≈ hi + lo with combined rel err ~2^-17 : fp32-emulation inputs for 3-term MFMA.
__global__ void split_kernel(const float* __restrict__ in, u16* __restrict__ hi,
                             u16* __restrict__ lo, int n) {
  int i = (blockIdx.x * blockDim.x + threadIdx.x) * 4;
  if (i + 4 > n) return;
  float4 f = *(const float4*)(in + i);
  ushort4 h, l;
  h.x = f2bf(f.x); l.x = f2bf(f.x - bf2f(h.x));
  h.y = f2bf(f.y); l.y = f2bf(f.y - bf2f(h.y));
  h.z = f2bf(f.z); l.z = f2bf(f.z - bf2f(h.z));
  h.w = f2bf(f.w); l.w = f2bf(f.w - bf2f(h.w));
  *(ushort4*)(hi + i) = h;
  *(ushort4*)(lo + i) = l;
}

// ---------------------------------------------------------------- LDS staging helper
typedef __attribute__((address_space(3))) void  lds_void;
typedef const __attribute__((address_space(1))) void g_void;
static __device__ __forceinline__ void load_lds16(const void* g, void* l) {
  __builtin_amdgcn_global_load_lds((g_void*)g, (lds_void*)l, 16, 0, 0);
}

// ---------------------------------------------------------------- plain bf16 GEMM (BT): C[m,n] = sum_k A[m,k]*B[n,k]
__global__ __launch_bounds__(256) void gemm_bt(const u16* __restrict__ A,
                                               const u16* __restrict__ Bw,
                                               u16* __restrict__ Cp,
                                               int M, int N, int K, float scale) {
  __shared__ u16 lA[128 * 32];
  __shared__ u16 lB[128 * 32];
  const int tid  = threadIdx.x;
  const int w    = tid >> 6;
  const int lane = tid & 63;
  const int m    = lane & 15;
  const int kg   = lane >> 4;
  const int m0   = blockIdx.y * 128;
  const int n0   = blockIdx.x * 128;
  const int wm   = (w >> 1) * 64;
  const int wn   = (w & 1) * 64;
  const int rowS = tid >> 2;
  const int part = tid & 3;

  floatx4 acc[4][4];
#pragma unroll
  for (int i = 0; i < 4; ++i)
#pragma unroll
    for (int j = 0; j < 4; ++j)
#pragma unroll
      for (int r = 0; r < 4; ++r) acc[i][j][r] = 0.0f;

  for (int k0 = 0; k0 < K; k0 += 32) {
    __syncthreads();
#pragma unroll
    for (int rnd = 0; rnd < 2; ++rnd) {
      const u16* ga = A  + (size_t)(m0 + rnd * 64 + rowS) * K + k0 + part * 8;
      const u16* gb = Bw + (size_t)(n0 + rnd * 64 + rowS) * K + k0 + part * 8;
      load_lds16(ga, lA + rnd * 2048 + w * 512);
      load_lds16(gb, lB + rnd * 2048 + w * 512);
    }
    __syncthreads();

    short8 af[4], bf[4];
#pragma unroll
    for (int i = 0; i < 4; ++i) af[i] = *(const short8*)&lA[(wm + i * 16 + m) * 32 + kg * 8];
#pragma unroll
    for (int i = 0; i < 4; ++i) bf[i] = *(const short8*)&lB[(wn + i * 16 + m) * 32 + kg * 8];
#pragma unroll
    for (int mi = 0; mi < 4; ++mi)
#pragma unroll
      for (int ni = 0; ni < 4; ++ni)
        acc[mi][ni] = __builtin_amdgcn_mfma_f32_16x16x32_bf16(af[mi], bf[ni], acc[mi][ni], 0, 0, 0);
  }

#pragma unroll
  for (int mi = 0; mi < 4; ++mi)
#pragma unroll
    for (int ni = 0; ni < 4; ++ni)
#pragma unroll
      for (int r = 0; r < 4; ++r) {
        int row = m0 + wm + mi * 16 + kg * 4 + r;
        int col = n0 + wn + ni * 16 + m;
        Cp[(size_t)row * N + col] = f2bf(acc[mi][ni][r] * scale);
      }
}

// ---------------------------------------------------------------- split-bf16 GEMM (fp32 emulation)
// C = (Ah+Al)(Bh+Bl)^T ≈ Ah·Bh + Ah·Bl + Al·Bh   (3-term MFMA, rel err ~2^-17)
// OUT==0: fp32 into C0.  OUT==2: hi bf16 into C0, lo bf16 into C1.
template <int OUT>
__global__ __launch_bounds__(256) void gemm_split(const u16* __restrict__ Ah,
                                                  const u16* __restrict__ Al,
                                                  const u16* __restrict__ Bh,
                                                  const u16* __restrict__ Bl,
                                                  void* __restrict__ C0,
                                                  u16* __restrict__ C1,
                                                  int M, int N, int K, float scale) {
  __shared__ u16 lAh[128 * 32];
  __shared__ u16 lAl[128 * 32];
  __shared__ u16 lBh[128 * 32];
  __shared__ u16 lBl[128 * 32];
  const int tid  = threadIdx.x;
  const int w    = tid >> 6;
  const int lane = tid & 63;
  const int m    = lane & 15;
  const int kg   = lane >> 4;
  const int m0   = blockIdx.y * 128;
  const int n0   = blockIdx.x * 128;
  const int wm   = (w >> 1) * 64;
  const int wn   = (w & 1) * 64;
  const int rowS = tid >> 2;
  const int part = tid & 3;

  floatx4 acc[4][4];
#pragma unroll
  for (int i = 0; i < 4; ++i)
#pragma unroll
    for (int j = 0; j < 4; ++j)
#pragma unroll
      for (int r = 0; r < 4; ++r) acc[i][j][r] = 0.0f;

  for (int k0 = 0; k0 < K; k0 += 32) {
    __syncthreads();
#pragma unroll
    for (int rnd = 0; rnd < 2; ++rnd) {
      size_t offA = (size_t)(m0 + rnd * 64 + rowS) * K + k0 + part * 8;
      size_t offB = (size_t)(n0 + rnd * 64 + rowS) * K + k0 + part * 8;
      int dst = rnd * 2048 + w * 512;
      load_lds16(Ah + offA, lAh + dst);
      load_lds16(Al + offA, lAl + dst);
      load_lds16(Bh + offB, lBh + dst);
      load_lds16(Bl + offB, lBl + dst);
    }
    __syncthreads();

    short8 afh[4], afl[4], bfh[4], bfl[4];
#pragma unroll
    for (int i = 0; i < 4; ++i) {
      int ao = (wm + i * 16 + m) * 32 + kg * 8;
      int bo = (wn + i * 16 + m) * 32 + kg * 8;
      afh[i] = *(const short8*)&lAh[ao];
      afl[i] = *(const short8*)&lAl[ao];
      bfh[i] = *(const short8*)&lBh[bo];
      bfl[i] = *(const short8*)&lBl[bo];
    }
#pragma unroll
    for (int mi = 0; mi < 4; ++mi)
#pragma unroll
      for (int ni = 0; ni < 4; ++ni) {
        acc[mi][ni] = __builtin_amdgcn_mfma_f32_16x16x32_bf16(afh[mi], bfh[ni], acc[mi][ni], 0, 0, 0);
        acc[mi][ni] = __builtin_amdgcn_mfma_f32_16x16x32_bf16(afh[mi], bfl[ni], acc[mi][ni], 0, 0, 0);
        acc[mi][ni] = __builtin_amdgcn_mfma_f32_16x16x32_bf16(afl[mi], bfh[ni], acc[mi][ni], 0, 0, 0);
      }
  }

#pragma unroll
  for (int mi = 0; mi < 4; ++mi)
#pragma unroll
    for (int ni = 0; ni < 4; ++ni)
#pragma unroll
      for (int r = 0; r < 4; ++r) {
        int row = m0 + wm + mi * 16 + kg * 4 + r;
        int col = n0 + wn + ni * 16 + m;
        size_t idx = (size_t)row * N + col;
        float vv = acc[mi][ni][r] * scale;
        if (OUT == 0) {
          ((float*)C0)[idx] = vv;
        } else {
          u16 h = f2bf(vv);
          ((u16*)C0)[idx] = h;
          C1[idx] = f2bf(vv - bf2f(h));
        }
      }
}

// ---------------------------------------------------------------- fused flash attention
// grid (L/64 q-tiles, B*H). 256 threads = 4 waves, each wave owns 16 q rows.
// q pre-scaled by 1/sqrt(DH); q,k carried as hi/lo bf16 pairs for fp32-accurate scores.
__global__ __launch_bounds__(256) void attn_kernel(const u16* __restrict__ qh,
                                                   const u16* __restrict__ ql,
                                                   const u16* __restrict__ kh,
                                                   const u16* __restrict__ kl,
                                                   const u16* __restrict__ v,
                                                   const float* __restrict__ mask,
                                                   u16* __restrict__ ohi,
                                                   u16* __restrict__ olo) {
  __shared__ u16 lKh[64][72];
  __shared__ u16 lKl[64][72];
  __shared__ u16 lV[64][72];
  __shared__ u16 lP[4][16][72];

  const int bh   = blockIdx.y;
  const int b    = bh >> 4;
  const int h    = bh & 15;
  const int qt   = blockIdx.x;
  const int tid  = threadIdx.x;
  const int w    = tid >> 6;
  const int lane = tid & 63;
  const int m    = lane & 15;
  const int kg   = lane >> 4;
  const int qr0  = qt * 64 + w * 16;

  // Q A-frags: A[m=lane&15][k=kg*8+j], hi and lo parts
  const size_t qbase = ((size_t)((b * L_ + qr0 + m) * H_ + h)) * DH_;
  short8 aqh0 = *(const short8*)(qh + qbase + kg * 8);
  short8 aqh1 = *(const short8*)(qh + qbase + 32 + kg * 8);
  short8 aql0 = *(const short8*)(ql + qbase + kg * 8);
  short8 aql1 = *(const short8*)(ql + qbase + 32 + kg * 8);

  floatx4 acc[4];
#pragma unroll
  for (int t = 0; t < 4; ++t)
#pragma unroll
    for (int r = 0; r < 4; ++r) acc[t][r] = 0.0f;
  float mrow[4], lrow[4];
#pragma unroll
  for (int r = 0; r < 4; ++r) { mrow[r] = -3.0e38f; lrow[r] = 0.0f; }

  for (int c = 0; c < 16; ++c) {
    const int nb = c * 64;
    __syncthreads();
#pragma unroll
    for (int it = 0; it < 2; ++it) {
      int cid  = it * 256 + tid;
      int row  = cid >> 3;
      int koff = (cid & 7) * 8;
      size_t gidx = ((size_t)((b * L_ + nb + row) * H_ + h)) * DH_ + koff;
      *(short8*)&lKh[row][koff] = *(const short8*)(kh + gidx);
      *(short8*)&lKl[row][koff] = *(const short8*)(kl + gidx);
      *(short8*)&lV[row][koff]  = *(const short8*)(v + gidx);
    }
    __syncthreads();

    // S = Q K^T with 3-term split emulation (hi*hi + hi*lo + lo*hi)
    floatx4 s[4];
#pragma unroll
    for (int t = 0; t < 4; ++t) {
      short8 bh0 = *(const short8*)&lKh[t * 16 + m][kg * 8];
      short8 bh1 = *(const short8*)&lKh[t * 16 + m][32 + kg * 8];
      short8 bl0 = *(const short8*)&lKl[t * 16 + m][kg * 8];
      short8 bl1 = *(const short8*)&lKl[t * 16 + m][32 + kg * 8];
      floatx4 z; z[0] = z[1] = z[2] = z[3] = 0.0f;
      z = __builtin_amdgcn_mfma_f32_16x16x32_bf16(aqh0, bh0, z, 0, 0, 0);
      z = __builtin_amdgcn_mfma_f32_16x16x32_bf16(aqh1, bh1, z, 0, 0, 0);
      z = __builtin_amdgcn_mfma_f32_16x16x32_bf16(aqh0, bl0, z, 0, 0, 0);
      z = __builtin_amdgcn_mfma_f32_16x16x32_bf16(aqh1, bl1, z, 0, 0, 0);
      z = __builtin_amdgcn_mfma_f32_16x16x32_bf16(aql0, bh0, z, 0, 0, 0);
      z = __builtin_amdgcn_mfma_f32_16x16x32_bf16(aql1, bh1, z, 0, 0, 0);
      s[t] = z;
    }

    // mask + online softmax (row r lives on the 16 lanes sharing kg)
#pragma unroll
    for (int r = 0; r < 4; ++r) {
      const float* mp = mask + (size_t)(qr0 + kg * 4 + r) * L_ + nb;
      float vals[4];
      float mx = -3.0e38f;
#pragma unroll
      for (int t = 0; t < 4; ++t) {
        float mv  = mp[t * 16 + m];
        float val = s[t][r] * mv - 1.25e8f * (1.0f - mv);  // scale pre-applied to q
        vals[t] = val;
        mx = fmaxf(mx, val);
      }
#pragma unroll
      for (int d = 1; d < 16; d <<= 1) mx = fmaxf(mx, __shfl_xor(mx, d, 64));
      float mnew  = fmaxf(mrow[r], mx);
      float alpha = __expf(mrow[r] - mnew);
      mrow[r] = mnew;
      float sum = 0.0f;
#pragma unroll
      for (int t = 0; t < 4; ++t) {
        float p = __expf(vals[t] - mnew);
        sum += p;
        lP[w][kg * 4 + r][t * 16 + m] = f2bf(p);
      }
#pragma unroll
      for (int d = 1; d < 16; d <<= 1) sum += __shfl_xor(sum, d, 64);
      lrow[r] = lrow[r] * alpha + sum;
#pragma unroll
      for (int t = 0; t < 4; ++t) acc[t][r] *= alpha;
    }
    __syncthreads();

    // O += P V
    short8 ap0 = *(const short8*)&lP[w][m][kg * 8];
    short8 ap1 = *(const short8*)&lP[w][m][32 + kg * 8];
#pragma unroll
    for (int t = 0; t < 4; ++t) {
      short8 b0, b1;
#pragma unroll
      for (int j = 0; j < 8; ++j) {
        b0[j] = (short)lV[kg * 8 + j][t * 16 + m];
        b1[j] = (short)lV[32 + kg * 8 + j][t * 16 + m];
      }
      acc[t] = __builtin_amdgcn_mfma_f32_16x16x32_bf16(ap0, b0, acc[t], 0, 0, 0);
      acc[t] = __builtin_amdgcn_mfma_f32_16x16x32_bf16(ap1, b1, acc[t], 0, 0, 0);
    }
  }

  // epilogue: normalize, split-store hi/lo bf16 (B,L,H,DH)
#pragma unroll
  for (int r = 0; r < 4; ++r) {
    float inv = 1.0f / lrow[r];
#pragma unroll
    for (int t = 0; t < 4; ++t) {
      float ov = acc[t][r] * inv;
      size_t idx = ((size_t)((b * L_ + qr0 + kg * 4 + r) * H_ + h)) * DH_ + t * 16 + m;
      u16 hh = f2bf(ov);
      ohi[idx] = hh;
      olo[idx] = f2bf(ov - bf2f(hh));
    }
  }
}

// ---------------------------------------------------------------- launch
extern "C" void kernel_launch(void* const* d_in, const int* in_sizes, int n_in,
                              void* d_out, int out_size, void* d_ws, size_t ws_size,
                              hipStream_t stream) {
  const float* x    = (const float*)d_in[0];
  const float* mask = (const float*)d_in[1];
  const float* Wk   = (const float*)d_in[2];
  const float* Wv   = (const float*)d_in[3];
  const float* Wq   = (const float*)d_in[4];
  const float* Wo   = (const float*)d_in[5];
  float* out = (float*)d_out;

  // ws layout (96 MB). x hi/lo reused as attention-output hi/lo after projections.
  char* ws = (char*)d_ws;
  u16* xhi  = (u16*)(ws);                    // 16 MB ; later attn hi
  u16* xlo  = (u16*)(ws + (16ull << 20));    // 16 MB ; later attn lo
  u16* khi  = (u16*)(ws + (32ull << 20));    // 16 MB
  u16* klo  = (u16*)(ws + (48ull << 20));    // 16 MB
  u16* vb   = (u16*)(ws + (64ull << 20));    // 16 MB
  u16* wqh  = (u16*)(ws + (80ull << 20));    // 2 MB each
  u16* wql  = (u16*)(ws + (82ull << 20));
  u16* wkh  = (u16*)(ws + (84ull << 20));
  u16* wkl  = (u16*)(ws + (86ull << 20));
  u16* wvh  = (u16*)(ws + (88ull << 20));
  u16* wvl  = (u16*)(ws + (90ull << 20));
  u16* woh  = (u16*)(ws + (92ull << 20));
  u16* wol  = (u16*)(ws + (94ull << 20));
  // q hi/lo live in d_out (32 MB, dead before the final GEMM writes it)
  u16* qhi  = (u16*)d_out;
  u16* qlo  = qhi + (size_t)B_ * L_ * D_;

  const int NX = B_ * L_ * D_;   // 8388608
  const int NW = D_ * D_;        // 1048576
  split_kernel<<<NX / 4 / 256, 256, 0, stream>>>(x,  xhi, xlo, NX);
  split_kernel<<<NW / 4 / 256, 256, 0, stream>>>(Wq, wqh, wql, NW);
  split_kernel<<<NW / 4 / 256, 256, 0, stream>>>(Wk, wkh, wkl, NW);
  split_kernel<<<NW / 4 / 256, 256, 0, stream>>>(Wv, wvh, wvl, NW);
  split_kernel<<<NW / 4 / 256, 256, 0, stream>>>(Wo, woh, wol, NW);

  dim3 gg(D_ / 128, (B_ * L_) / 128);   // (8, 64)
  // q = x Wq^T * 1/8 (scale exact pow2, applied before hi/lo split of q)
  gemm_split<2><<<gg, 256, 0, stream>>>(xhi, xlo, wqh, wql, qhi, qlo, B_ * L_, D_, D_, 0.125f);
  gemm_split<2><<<gg, 256, 0, stream>>>(xhi, xlo, wkh, wkl, khi, klo, B_ * L_, D_, D_, 1.0f);
  gemm_bt<<<gg, 256, 0, stream>>>(xhi, wvh, vb, B_ * L_, D_, D_, 1.0f);

  dim3 ga(L_ / 64, B_ * H_);            // (16, 128)
  attn_kernel<<<ga, 256, 0, stream>>>(qhi, qlo, khi, klo, vb, mask, xhi, xlo);

  gemm_split<0><<<gg, 256, 0, stream>>>(xhi, xlo, woh, wol, out, nullptr, B_ * L_, D_, D_, 1.0f);
}

// Round 3
// 472.660 us; speedup vs baseline: 1.2078x; 1.2078x over previous
//
#include <hip/hip_runtime.h>

// Problem constants (B=8, L=1024, D=1024, H=16, DH=64)
#define B_  8
#define L_  1024
#define D_  1024
#define H_  16
#define DH_ 64

typedef unsigned short u16;
typedef __attribute__((ext_vector_type(8))) short short8;   // 8 x bf16 (4 VGPRs)
typedef __attribute__((ext_vector_type(4))) float floatx4;  // MFMA 16x16 C/D frag

// fp32 -> bf16 round-to-nearest-even
static __device__ __forceinline__ u16 f2bf(float f) {
  union { float f; unsigned u; } cv; cv.f = f;
  unsigned u = cv.u;
  return (u16)((u + 0x7fffu + ((u >> 16) & 1u)) >> 16);
}
static __device__ __forceinline__ float bf2f(u16 h) {
  union { unsigned u; float f; } cv; cv.u = ((unsigned)h) << 16;
  return cv.f;
}

// ---------------------------------------------------------------- split f32 -> (hi, lo) bf16
__global__ void split_kernel(const float* __restrict__ in, u16* __restrict__ hi,
                             u16* __restrict__ lo, int n) {
  int i = (blockIdx.x * blockDim.x + threadIdx.x) * 4;
  if (i + 4 > n) return;
  float4 f = *(const float4*)(in + i);
  ushort4 h, l;
  h.x = f2bf(f.x); l.x = f2bf(f.x - bf2f(h.x));
  h.y = f2bf(f.y); l.y = f2bf(f.y - bf2f(h.y));
  h.z = f2bf(f.z); l.z = f2bf(f.z - bf2f(h.z));
  h.w = f2bf(f.w); l.w = f2bf(f.w - bf2f(h.w));
  *(ushort4*)(hi + i) = h;
  *(ushort4*)(lo + i) = l;
}

// ---------------------------------------------------------------- LDS staging helper
typedef __attribute__((address_space(3))) void  lds_void;
typedef const __attribute__((address_space(1))) void g_void;
static __device__ __forceinline__ void load_lds16(const void* g, void* l) {
  __builtin_amdgcn_global_load_lds((g_void*)g, (lds_void*)l, 16, 0, 0);
}

// ---------------------------------------------------------------- plain bf16 GEMM (BT)
__global__ __launch_bounds__(256) void gemm_bt(const u16* __restrict__ A,
                                               const u16* __restrict__ Bw,
                                               u16* __restrict__ Cp,
                                               int M, int N, int K, float scale) {
  __shared__ u16 lA[128 * 32];
  __shared__ u16 lB[128 * 32];
  const int tid  = threadIdx.x;
  const int w    = tid >> 6;
  const int lane = tid & 63;
  const int m    = lane & 15;
  const int kg   = lane >> 4;
  const int m0   = blockIdx.y * 128;
  const int n0   = blockIdx.x * 128;
  const int wm   = (w >> 1) * 64;
  const int wn   = (w & 1) * 64;
  const int rowS = tid >> 2;
  const int part = tid & 3;

  floatx4 acc[4][4];
#pragma unroll
  for (int i = 0; i < 4; ++i)
#pragma unroll
    for (int j = 0; j < 4; ++j)
#pragma unroll
      for (int r = 0; r < 4; ++r) acc[i][j][r] = 0.0f;

  for (int k0 = 0; k0 < K; k0 += 32) {
    __syncthreads();
#pragma unroll
    for (int rnd = 0; rnd < 2; ++rnd) {
      const u16* ga = A  + (size_t)(m0 + rnd * 64 + rowS) * K + k0 + part * 8;
      const u16* gb = Bw + (size_t)(n0 + rnd * 64 + rowS) * K + k0 + part * 8;
      load_lds16(ga, lA + rnd * 2048 + w * 512);
      load_lds16(gb, lB + rnd * 2048 + w * 512);
    }
    __syncthreads();

    short8 af[4], bf[4];
#pragma unroll
    for (int i = 0; i < 4; ++i) af[i] = *(const short8*)&lA[(wm + i * 16 + m) * 32 + kg * 8];
#pragma unroll
    for (int i = 0; i < 4; ++i) bf[i] = *(const short8*)&lB[(wn + i * 16 + m) * 32 + kg * 8];
#pragma unroll
    for (int mi = 0; mi < 4; ++mi)
#pragma unroll
      for (int ni = 0; ni < 4; ++ni)
        acc[mi][ni] = __builtin_amdgcn_mfma_f32_16x16x32_bf16(af[mi], bf[ni], acc[mi][ni], 0, 0, 0);
  }

#pragma unroll
  for (int mi = 0; mi < 4; ++mi)
#pragma unroll
    for (int ni = 0; ni < 4; ++ni)
#pragma unroll
      for (int r = 0; r < 4; ++r) {
        int row = m0 + wm + mi * 16 + kg * 4 + r;
        int col = n0 + wn + ni * 16 + m;
        Cp[(size_t)row * N + col] = f2bf(acc[mi][ni][r] * scale);
      }
}

// ---------------------------------------------------------------- split-bf16 GEMM (fp32 emulation)
template <int OUT>
__global__ __launch_bounds__(256) void gemm_split(const u16* __restrict__ Ah,
                                                  const u16* __restrict__ Al,
                                                  const u16* __restrict__ Bh,
                                                  const u16* __restrict__ Bl,
                                                  void* __restrict__ C0,
                                                  u16* __restrict__ C1,
                                                  int M, int N, int K, float scale) {
  __shared__ u16 lAh[128 * 32];
  __shared__ u16 lAl[128 * 32];
  __shared__ u16 lBh[128 * 32];
  __shared__ u16 lBl[128 * 32];
  const int tid  = threadIdx.x;
  const int w    = tid >> 6;
  const int lane = tid & 63;
  const int m    = lane & 15;
  const int kg   = lane >> 4;
  const int m0   = blockIdx.y * 128;
  const int n0   = blockIdx.x * 128;
  const int wm   = (w >> 1) * 64;
  const int wn   = (w & 1) * 64;
  const int rowS = tid >> 2;
  const int part = tid & 3;

  floatx4 acc[4][4];
#pragma unroll
  for (int i = 0; i < 4; ++i)
#pragma unroll
    for (int j = 0; j < 4; ++j)
#pragma unroll
      for (int r = 0; r < 4; ++r) acc[i][j][r] = 0.0f;

  for (int k0 = 0; k0 < K; k0 += 32) {
    __syncthreads();
#pragma unroll
    for (int rnd = 0; rnd < 2; ++rnd) {
      size_t offA = (size_t)(m0 + rnd * 64 + rowS) * K + k0 + part * 8;
      size_t offB = (size_t)(n0 + rnd * 64 + rowS) * K + k0 + part * 8;
      int dst = rnd * 2048 + w * 512;
      load_lds16(Ah + offA, lAh + dst);
      load_lds16(Al + offA, lAl + dst);
      load_lds16(Bh + offB, lBh + dst);
      load_lds16(Bl + offB, lBl + dst);
    }
    __syncthreads();

    short8 afh[4], afl[4], bfh[4], bfl[4];
#pragma unroll
    for (int i = 0; i < 4; ++i) {
      int ao = (wm + i * 16 + m) * 32 + kg * 8;
      int bo = (wn + i * 16 + m) * 32 + kg * 8;
      afh[i] = *(const short8*)&lAh[ao];
      afl[i] = *(const short8*)&lAl[ao];
      bfh[i] = *(const short8*)&lBh[bo];
      bfl[i] = *(const short8*)&lBl[bo];
    }
#pragma unroll
    for (int mi = 0; mi < 4; ++mi)
#pragma unroll
      for (int ni = 0; ni < 4; ++ni) {
        acc[mi][ni] = __builtin_amdgcn_mfma_f32_16x16x32_bf16(afh[mi], bfh[ni], acc[mi][ni], 0, 0, 0);
        acc[mi][ni] = __builtin_amdgcn_mfma_f32_16x16x32_bf16(afh[mi], bfl[ni], acc[mi][ni], 0, 0, 0);
        acc[mi][ni] = __builtin_amdgcn_mfma_f32_16x16x32_bf16(afl[mi], bfh[ni], acc[mi][ni], 0, 0, 0);
      }
  }

#pragma unroll
  for (int mi = 0; mi < 4; ++mi)
#pragma unroll
    for (int ni = 0; ni < 4; ++ni)
#pragma unroll
      for (int r = 0; r < 4; ++r) {
        int row = m0 + wm + mi * 16 + kg * 4 + r;
        int col = n0 + wn + ni * 16 + m;
        size_t idx = (size_t)row * N + col;
        float vv = acc[mi][ni][r] * scale;
        if (OUT == 0) {
          ((float*)C0)[idx] = vv;
        } else {
          u16 h = f2bf(vv);
          ((u16*)C0)[idx] = h;
          C1[idx] = f2bf(vv - bf2f(h));
        }
      }
}

// ---------------------------------------------------------------- fused flash attention
// grid (L/64 q-tiles, B*H). 256 threads = 4 waves, each wave owns 16 q rows.
// V stored TRANSPOSED in LDS (lVt[dh][key]) so PV B-frags are ds_read_b128.
// K hi/lo + V for chunk c+1 prefetched into registers during chunk c compute.
__global__ __launch_bounds__(256) void attn_kernel(const u16* __restrict__ qh,
                                                   const u16* __restrict__ ql,
                                                   const u16* __restrict__ kh,
                                                   const u16* __restrict__ kl,
                                                   const u16* __restrict__ v,
                                                   const float* __restrict__ mask,
                                                   u16* __restrict__ ohi,
                                                   u16* __restrict__ olo) {
  __shared__ u16 lKh[64][72];      // [key][dh]  stride 72 (144B, 16B-aligned)
  __shared__ u16 lKl[64][72];
  __shared__ u16 lVt[64][72];      // [dh][key]  transposed V
  __shared__ u16 lP[4][16][72];    // per-wave P tile (wave-private: no barrier needed)

  const int bh   = blockIdx.y;
  const int b    = bh >> 4;
  const int h    = bh & 15;
  const int qt   = blockIdx.x;
  const int tid  = threadIdx.x;
  const int w    = tid >> 6;
  const int lane = tid & 63;
  const int m    = lane & 15;
  const int kg   = lane >> 4;
  const int qr0  = qt * 64 + w * 16;

  // staging index precompute
  const int srow[2]  = { tid >> 3, 32 + (tid >> 3) };          // K row per it
  const int skoff    = (tid & 7) * 8;                          // K dh offset
  const int sdh      = lane;                                   // V: lane = dh (coalesced)
  const int skey0[2] = { w * 8, 32 + w * 8 };                  // V key group per it

  // Q A-frags: A[m=lane&15][k=kg*8+j], hi and lo parts
  const size_t qbase = ((size_t)((b * L_ + qr0 + m) * H_ + h)) * DH_;
  short8 aqh0 = *(const short8*)(qh + qbase + kg * 8);
  short8 aqh1 = *(const short8*)(qh + qbase + 32 + kg * 8);
  short8 aql0 = *(const short8*)(ql + qbase + kg * 8);
  short8 aql1 = *(const short8*)(ql + qbase + 32 + kg * 8);

  floatx4 acc[4];
#pragma unroll
  for (int t = 0; t < 4; ++t)
#pragma unroll
    for (int r = 0; r < 4; ++r) acc[t][r] = 0.0f;
  float mrow[4], lrow[4];
#pragma unroll
  for (int r = 0; r < 4; ++r) { mrow[r] = -3.0e38f; lrow[r] = 0.0f; }

  short8 rkh[2], rkl[2], rv[2];
  // prefetch chunk 0
#pragma unroll
  for (int it = 0; it < 2; ++it) {
    size_t gk = ((size_t)((b * L_ + srow[it]) * H_ + h)) * DH_ + skoff;
    rkh[it] = *(const short8*)(kh + gk);
    rkl[it] = *(const short8*)(kl + gk);
    short8 tmp;
#pragma unroll
    for (int j = 0; j < 8; ++j)
      tmp[j] = (short)v[((size_t)((b * L_ + skey0[it] + j) * H_ + h)) * DH_ + sdh];
    rv[it] = tmp;
  }

  for (int c = 0; c < 16; ++c) {
    const int nb = c * 64;
    __syncthreads();               // previous chunk's lK/lVt readers done
#pragma unroll
    for (int it = 0; it < 2; ++it) {
      *(short8*)&lKh[srow[it]][skoff] = rkh[it];
      *(short8*)&lKl[srow[it]][skoff] = rkl[it];
      *(short8*)&lVt[sdh][skey0[it]]  = rv[it];
    }
    __syncthreads();               // staging visible to all waves

    // prefetch chunk c+1 (overlaps global latency with compute below)
    if (c < 15) {
      const int nb2 = nb + 64;
#pragma unroll
      for (int it = 0; it < 2; ++it) {
        size_t gk = ((size_t)((b * L_ + nb2 + srow[it]) * H_ + h)) * DH_ + skoff;
        rkh[it] = *(const short8*)(kh + gk);
        rkl[it] = *(const short8*)(kl + gk);
        short8 tmp;
#pragma unroll
        for (int j = 0; j < 8; ++j)
          tmp[j] = (short)v[((size_t)((b * L_ + nb2 + skey0[it] + j) * H_ + h)) * DH_ + sdh];
        rv[it] = tmp;
      }
    }

    // S = Q K^T with 3-term split emulation
    floatx4 s[4];
#pragma unroll
    for (int t = 0; t < 4; ++t) {
      short8 bh0 = *(const short8*)&lKh[t * 16 + m][kg * 8];
      short8 bh1 = *(const short8*)&lKh[t * 16 + m][32 + kg * 8];
      short8 bl0 = *(const short8*)&lKl[t * 16 + m][kg * 8];
      short8 bl1 = *(const short8*)&lKl[t * 16 + m][32 + kg * 8];
      floatx4 z; z[0] = z[1] = z[2] = z[3] = 0.0f;
      z = __builtin_amdgcn_mfma_f32_16x16x32_bf16(aqh0, bh0, z, 0, 0, 0);
      z = __builtin_amdgcn_mfma_f32_16x16x32_bf16(aqh1, bh1, z, 0, 0, 0);
      z = __builtin_amdgcn_mfma_f32_16x16x32_bf16(aqh0, bl0, z, 0, 0, 0);
      z = __builtin_amdgcn_mfma_f32_16x16x32_bf16(aqh1, bl1, z, 0, 0, 0);
      z = __builtin_amdgcn_mfma_f32_16x16x32_bf16(aql0, bh0, z, 0, 0, 0);
      z = __builtin_amdgcn_mfma_f32_16x16x32_bf16(aql1, bh1, z, 0, 0, 0);
      s[t] = z;
    }

    // mask + online softmax (row r lives on the 16 lanes sharing kg)
#pragma unroll
    for (int r = 0; r < 4; ++r) {
      const float* mp = mask + (size_t)(qr0 + kg * 4 + r) * L_ + nb;
      float vals[4];
      float mx = -3.0e38f;
#pragma unroll
      for (int t = 0; t < 4; ++t) {
        float mv  = mp[t * 16 + m];
        float val = s[t][r] * mv - 1.25e8f * (1.0f - mv);
        vals[t] = val;
        mx = fmaxf(mx, val);
      }
#pragma unroll
      for (int d = 1; d < 16; d <<= 1) mx = fmaxf(mx, __shfl_xor(mx, d, 64));
      float mnew  = fmaxf(mrow[r], mx);
      float alpha = __expf(mrow[r] - mnew);
      mrow[r] = mnew;
      float sum = 0.0f;
#pragma unroll
      for (int t = 0; t < 4; ++t) {
        float p = __expf(vals[t] - mnew);
        sum += p;
        lP[w][kg * 4 + r][t * 16 + m] = f2bf(p);
      }
#pragma unroll
      for (int d = 1; d < 16; d <<= 1) sum += __shfl_xor(sum, d, 64);
      lrow[r] = lrow[r] * alpha + sum;
#pragma unroll
      for (int t = 0; t < 4; ++t) acc[t][r] *= alpha;
    }
    // NOTE: no __syncthreads here — lP[w] is wave-private; in-wave DS ordering suffices.

    // O += P V : both operands vector b128 from LDS
    short8 ap0 = *(const short8*)&lP[w][m][kg * 8];
    short8 ap1 = *(const short8*)&lP[w][m][32 + kg * 8];
#pragma unroll
    for (int t = 0; t < 4; ++t) {
      short8 b0 = *(const short8*)&lVt[t * 16 + m][kg * 8];
      short8 b1 = *(const short8*)&lVt[t * 16 + m][32 + kg * 8];
      acc[t] = __builtin_amdgcn_mfma_f32_16x16x32_bf16(ap0, b0, acc[t], 0, 0, 0);
      acc[t] = __builtin_amdgcn_mfma_f32_16x16x32_bf16(ap1, b1, acc[t], 0, 0, 0);
    }
  }

  // epilogue: normalize, split-store hi/lo bf16 (B,L,H,DH)
#pragma unroll
  for (int r = 0; r < 4; ++r) {
    float inv = 1.0f / lrow[r];
#pragma unroll
    for (int t = 0; t < 4; ++t) {
      float ov = acc[t][r] * inv;
      size_t idx = ((size_t)((b * L_ + qr0 + kg * 4 + r) * H_ + h)) * DH_ + t * 16 + m;
      u16 hh = f2bf(ov);
      ohi[idx] = hh;
      olo[idx] = f2bf(ov - bf2f(hh));
    }
  }
}

// ---------------------------------------------------------------- launch
extern "C" void kernel_launch(void* const* d_in, const int* in_sizes, int n_in,
                              void* d_out, int out_size, void* d_ws, size_t ws_size,
                              hipStream_t stream) {
  const float* x    = (const float*)d_in[0];
  const float* mask = (const float*)d_in[1];
  const float* Wk   = (const float*)d_in[2];
  const float* Wv   = (const float*)d_in[3];
  const float* Wq   = (const float*)d_in[4];
  const float* Wo   = (const float*)d_in[5];
  float* out = (float*)d_out;

  char* ws = (char*)d_ws;
  u16* xhi  = (u16*)(ws);                    // 16 MB ; later attn hi
  u16* xlo  = (u16*)(ws + (16ull << 20));    // 16 MB ; later attn lo
  u16* khi  = (u16*)(ws + (32ull << 20));
  u16* klo  = (u16*)(ws + (48ull << 20));
  u16* vb   = (u16*)(ws + (64ull << 20));
  u16* wqh  = (u16*)(ws + (80ull << 20));
  u16* wql  = (u16*)(ws + (82ull << 20));
  u16* wkh  = (u16*)(ws + (84ull << 20));
  u16* wkl  = (u16*)(ws + (86ull << 20));
  u16* wvh  = (u16*)(ws + (88ull << 20));
  u16* wvl  = (u16*)(ws + (90ull << 20));
  u16* woh  = (u16*)(ws + (92ull << 20));
  u16* wol  = (u16*)(ws + (94ull << 20));
  u16* qhi  = (u16*)d_out;                   // q hi/lo live in d_out (dead until final GEMM)
  u16* qlo  = qhi + (size_t)B_ * L_ * D_;

  const int NX = B_ * L_ * D_;
  const int NW = D_ * D_;
  split_kernel<<<NX / 4 / 256, 256, 0, stream>>>(x,  xhi, xlo, NX);
  split_kernel<<<NW / 4 / 256, 256, 0, stream>>>(Wq, wqh, wql, NW);
  split_kernel<<<NW / 4 / 256, 256, 0, stream>>>(Wk, wkh, wkl, NW);
  split_kernel<<<NW / 4 / 256, 256, 0, stream>>>(Wv, wvh, wvl, NW);
  split_kernel<<<NW / 4 / 256, 256, 0, stream>>>(Wo, woh, wol, NW);

  dim3 gg(D_ / 128, (B_ * L_) / 128);
  gemm_split<2><<<gg, 256, 0, stream>>>(xhi, xlo, wqh, wql, qhi, qlo, B_ * L_, D_, D_, 0.125f);
  gemm_split<2><<<gg, 256, 0, stream>>>(xhi, xlo, wkh, wkl, khi, klo, B_ * L_, D_, D_, 1.0f);
  gemm_bt<<<gg, 256, 0, stream>>>(xhi, wvh, vb, B_ * L_, D_, D_, 1.0f);

  dim3 ga(L_ / 64, B_ * H_);
  attn_kernel<<<ga, 256, 0, stream>>>(qhi, qlo, khi, klo, vb, mask, xhi, xlo);

  gemm_split<0><<<gg, 256, 0, stream>>>(xhi, xlo, woh, wol, out, nullptr, B_ * L_, D_, D_, 1.0f);
}

// Round 4
// 405.883 us; speedup vs baseline: 1.4065x; 1.1645x over previous
//
#include <hip/hip_runtime.h>

// Problem constants (B=8, L=1024, D=1024, H=16, DH=64)
#define B_  8
#define L_  1024
#define D_  1024
#define H_  16
#define DH_ 64

typedef unsigned short u16;
typedef __attribute__((ext_vector_type(8))) short short8;   // 8 x bf16 (4 VGPRs)
typedef __attribute__((ext_vector_type(4))) float floatx4;  // MFMA 16x16 C/D frag

// fp32 -> bf16 round-to-nearest-even
static __device__ __forceinline__ u16 f2bf(float f) {
  union { float f; unsigned u; } cv; cv.f = f;
  unsigned u = cv.u;
  return (u16)((u + 0x7fffu + ((u >> 16) & 1u)) >> 16);
}
static __device__ __forceinline__ float bf2f(u16 h) {
  union { unsigned u; float f; } cv; cv.u = ((unsigned)h) << 16;
  return cv.f;
}
// pack two fp32 -> two bf16 (round-half-up; inputs are nonneg softmax weights)
static __device__ __forceinline__ unsigned pack_bf2(float a, float b) {
  union { float f; unsigned u; } ua, ub; ua.f = a; ub.f = b;
  return ((ua.u + 0x8000u) >> 16) | ((ub.u + 0x8000u) & 0xffff0000u);
}

// ---------------------------------------------------------------- casts
__global__ void split_kernel(const float* __restrict__ in, u16* __restrict__ hi,
                             u16* __restrict__ lo, int n) {
  int i = (blockIdx.x * blockDim.x + threadIdx.x) * 4;
  if (i + 4 > n) return;
  float4 f = *(const float4*)(in + i);
  ushort4 h, l;
  h.x = f2bf(f.x); l.x = f2bf(f.x - bf2f(h.x));
  h.y = f2bf(f.y); l.y = f2bf(f.y - bf2f(h.y));
  h.z = f2bf(f.z); l.z = f2bf(f.z - bf2f(h.z));
  h.w = f2bf(f.w); l.w = f2bf(f.w - bf2f(h.w));
  *(ushort4*)(hi + i) = h;
  *(ushort4*)(lo + i) = l;
}

__global__ void cast_kernel(const float* __restrict__ in, u16* __restrict__ out, int n) {
  int i = (blockIdx.x * blockDim.x + threadIdx.x) * 4;
  if (i + 4 > n) return;
  float4 f = *(const float4*)(in + i);
  ushort4 r;
  r.x = f2bf(f.x); r.y = f2bf(f.y); r.z = f2bf(f.z); r.w = f2bf(f.w);
  *(ushort4*)(out + i) = r;
}

// mask -> additive bias, with fixed softmax shift (-24) folded in.
// masked: -1.25e8 (matches ref's -1e9*scale exactly in effect); unmasked: -24.
__global__ void bias_kernel(const float* __restrict__ mask, float* __restrict__ bias, int n) {
  int i = (blockIdx.x * blockDim.x + threadIdx.x) * 4;
  if (i + 4 > n) return;
  float4 mv = *(const float4*)(mask + i);
  float4 o;
  o.x = (mv.x - 1.0f) * 1.25e8f - 24.0f;
  o.y = (mv.y - 1.0f) * 1.25e8f - 24.0f;
  o.z = (mv.z - 1.0f) * 1.25e8f - 24.0f;
  o.w = (mv.w - 1.0f) * 1.25e8f - 24.0f;
  *(float4*)(bias + i) = o;
}

// ---------------------------------------------------------------- LDS staging helper
typedef __attribute__((address_space(3))) void  lds_void;
typedef const __attribute__((address_space(1))) void g_void;
static __device__ __forceinline__ void load_lds16(const void* g, void* l) {
  __builtin_amdgcn_global_load_lds((g_void*)g, (lds_void*)l, 16, 0, 0);
}

// ---------------------------------------------------------------- plain bf16 GEMM (BT)
__global__ __launch_bounds__(256) void gemm_bt(const u16* __restrict__ A,
                                               const u16* __restrict__ Bw,
                                               u16* __restrict__ Cp,
                                               int M, int N, int K, float scale) {
  __shared__ u16 lA[128 * 32];
  __shared__ u16 lB[128 * 32];
  const int tid  = threadIdx.x;
  const int w    = tid >> 6;
  const int lane = tid & 63;
  const int m    = lane & 15;
  const int kg   = lane >> 4;
  const int m0   = blockIdx.y * 128;
  const int n0   = blockIdx.x * 128;
  const int wm   = (w >> 1) * 64;
  const int wn   = (w & 1) * 64;
  const int rowS = tid >> 2;
  const int part = tid & 3;

  floatx4 acc[4][4];
#pragma unroll
  for (int i = 0; i < 4; ++i)
#pragma unroll
    for (int j = 0; j < 4; ++j)
#pragma unroll
      for (int r = 0; r < 4; ++r) acc[i][j][r] = 0.0f;

  for (int k0 = 0; k0 < K; k0 += 32) {
    __syncthreads();
#pragma unroll
    for (int rnd = 0; rnd < 2; ++rnd) {
      const u16* ga = A  + (size_t)(m0 + rnd * 64 + rowS) * K + k0 + part * 8;
      const u16* gb = Bw + (size_t)(n0 + rnd * 64 + rowS) * K + k0 + part * 8;
      load_lds16(ga, lA + rnd * 2048 + w * 512);
      load_lds16(gb, lB + rnd * 2048 + w * 512);
    }
    __syncthreads();

    short8 af[4], bf[4];
#pragma unroll
    for (int i = 0; i < 4; ++i) af[i] = *(const short8*)&lA[(wm + i * 16 + m) * 32 + kg * 8];
#pragma unroll
    for (int i = 0; i < 4; ++i) bf[i] = *(const short8*)&lB[(wn + i * 16 + m) * 32 + kg * 8];
#pragma unroll
    for (int mi = 0; mi < 4; ++mi)
#pragma unroll
      for (int ni = 0; ni < 4; ++ni)
        acc[mi][ni] = __builtin_amdgcn_mfma_f32_16x16x32_bf16(af[mi], bf[ni], acc[mi][ni], 0, 0, 0);
  }

#pragma unroll
  for (int mi = 0; mi < 4; ++mi)
#pragma unroll
    for (int ni = 0; ni < 4; ++ni)
#pragma unroll
      for (int r = 0; r < 4; ++r) {
        int row = m0 + wm + mi * 16 + kg * 4 + r;
        int col = n0 + wn + ni * 16 + m;
        Cp[(size_t)row * N + col] = f2bf(acc[mi][ni][r] * scale);
      }
}

// ---------------------------------------------------------------- split-bf16 GEMM (fp32 emulation)
// TERMS==3: Ah·Bh + Ah·Bl + Al·Bh.  TERMS==2: (Ah+Al)·Bh (Bl unused).
template <int OUT, int TERMS>
__global__ __launch_bounds__(256) void gemm_split(const u16* __restrict__ Ah,
                                                  const u16* __restrict__ Al,
                                                  const u16* __restrict__ Bh,
                                                  const u16* __restrict__ Bl,
                                                  void* __restrict__ C0,
                                                  u16* __restrict__ C1,
                                                  int M, int N, int K, float scale) {
  __shared__ u16 lAh[128 * 32];
  __shared__ u16 lAl[128 * 32];
  __shared__ u16 lBh[128 * 32];
  __shared__ u16 lBl[128 * 32];
  const int tid  = threadIdx.x;
  const int w    = tid >> 6;
  const int lane = tid & 63;
  const int m    = lane & 15;
  const int kg   = lane >> 4;
  const int m0   = blockIdx.y * 128;
  const int n0   = blockIdx.x * 128;
  const int wm   = (w >> 1) * 64;
  const int wn   = (w & 1) * 64;
  const int rowS = tid >> 2;
  const int part = tid & 3;

  floatx4 acc[4][4];
#pragma unroll
  for (int i = 0; i < 4; ++i)
#pragma unroll
    for (int j = 0; j < 4; ++j)
#pragma unroll
      for (int r = 0; r < 4; ++r) acc[i][j][r] = 0.0f;

  for (int k0 = 0; k0 < K; k0 += 32) {
    __syncthreads();
#pragma unroll
    for (int rnd = 0; rnd < 2; ++rnd) {
      size_t offA = (size_t)(m0 + rnd * 64 + rowS) * K + k0 + part * 8;
      size_t offB = (size_t)(n0 + rnd * 64 + rowS) * K + k0 + part * 8;
      int dst = rnd * 2048 + w * 512;
      load_lds16(Ah + offA, lAh + dst);
      load_lds16(Al + offA, lAl + dst);
      load_lds16(Bh + offB, lBh + dst);
      if (TERMS == 3) load_lds16(Bl + offB, lBl + dst);
    }
    __syncthreads();

    short8 afh[4], afl[4], bfh[4], bfl[4];
#pragma unroll
    for (int i = 0; i < 4; ++i) {
      int ao = (wm + i * 16 + m) * 32 + kg * 8;
      int bo = (wn + i * 16 + m) * 32 + kg * 8;
      afh[i] = *(const short8*)&lAh[ao];
      afl[i] = *(const short8*)&lAl[ao];
      bfh[i] = *(const short8*)&lBh[bo];
      if (TERMS == 3) bfl[i] = *(const short8*)&lBl[bo];
    }
#pragma unroll
    for (int mi = 0; mi < 4; ++mi)
#pragma unroll
      for (int ni = 0; ni < 4; ++ni) {
        acc[mi][ni] = __builtin_amdgcn_mfma_f32_16x16x32_bf16(afh[mi], bfh[ni], acc[mi][ni], 0, 0, 0);
        if (TERMS == 3)
          acc[mi][ni] = __builtin_amdgcn_mfma_f32_16x16x32_bf16(afh[mi], bfl[ni], acc[mi][ni], 0, 0, 0);
        acc[mi][ni] = __builtin_amdgcn_mfma_f32_16x16x32_bf16(afl[mi], bfh[ni], acc[mi][ni], 0, 0, 0);
      }
  }

#pragma unroll
  for (int mi = 0; mi < 4; ++mi)
#pragma unroll
    for (int ni = 0; ni < 4; ++ni)
#pragma unroll
      for (int r = 0; r < 4; ++r) {
        int row = m0 + wm + mi * 16 + kg * 4 + r;
        int col = n0 + wn + ni * 16 + m;
        size_t idx = (size_t)row * N + col;
        float vv = acc[mi][ni][r] * scale;
        if (OUT == 0) {
          ((float*)C0)[idx] = vv;
        } else {
          u16 h = f2bf(vv);
          ((u16*)C0)[idx] = h;
          C1[idx] = f2bf(vv - bf2f(h));
        }
      }
}

// ---------------------------------------------------------------- V transpose (+key permutation)
// v (B,L,H,DH) -> vt[(b*H+h)*DH+dh][L], with keys permuted within each 64-chunk:
// position p holds key l = ((p&3)<<4) + (p>>2)   (inverse of key t*16+mm -> pos mm*4+t)
__global__ __launch_bounds__(256) void transpose_v(const u16* __restrict__ v,
                                                   u16* __restrict__ vt) {
  __shared__ u16 lds[64][72];
  const int b  = blockIdx.y >> 4;
  const int h  = blockIdx.y & 15;
  const int l0 = blockIdx.x * 64;
  const int tid = threadIdx.x;
#pragma unroll
  for (int it = 0; it < 2; ++it) {
    int idx = it * 256 + tid;
    int i = idx >> 3, off = (idx & 7) * 8;
    *(short8*)&lds[i][off] =
        *(const short8*)(v + ((size_t)(b * L_ + l0 + i)) * D_ + h * 64 + off);
  }
  __syncthreads();
  const int j  = tid >> 2;
  const int p0 = (tid & 3) * 16;
  __attribute__((aligned(16))) u16 tmp[16];
#pragma unroll
  for (int s = 0; s < 16; ++s) {
    int p = p0 + s;
    int l = ((p & 3) << 4) + (p >> 2);
    tmp[s] = lds[l][j];
  }
  u16* dst = vt + ((size_t)((b * H_ + h) * DH_ + j)) * L_ + l0 + p0;
  *(short8*)(dst)     = *(const short8*)&tmp[0];
  *(short8*)(dst + 8) = *(const short8*)&tmp[8];
}

// ---------------------------------------------------------------- fused flash attention
// Fixed-shift softmax (shift folded into bias), deferred sum reduction,
// permuted-contiguous P writes (b64), V pre-transposed+permuted.
__global__ __launch_bounds__(256, 4) void attn_kernel(const u16* __restrict__ qh,
                                                      const u16* __restrict__ ql,
                                                      const u16* __restrict__ kh,
                                                      const u16* __restrict__ kl,
                                                      const u16* __restrict__ vt,
                                                      const float* __restrict__ bias,
                                                      u16* __restrict__ ohi,
                                                      u16* __restrict__ olo) {
  __shared__ u16 lKh[64][72];
  __shared__ u16 lKl[64][72];
  __shared__ u16 lVt[64][72];      // [dh][key-pos] (permuted)
  __shared__ u16 lP[4][16][72];    // wave-private P, permuted-key layout

  const int bh   = blockIdx.y;
  const int b    = bh >> 4;
  const int h    = bh & 15;
  const int qt   = blockIdx.x;
  const int tid  = threadIdx.x;
  const int w    = tid >> 6;
  const int lane = tid & 63;
  const int m    = lane & 15;
  const int kg   = lane >> 4;
  const int qr0  = qt * 64 + w * 16;

  const int srow  = tid >> 3;        // 0..31 (+32 on second round)
  const int skoff = (tid & 7) * 8;

  const size_t qbase = ((size_t)((b * L_ + qr0 + m) * H_ + h)) * DH_;
  short8 aqh0 = *(const short8*)(qh + qbase + kg * 8);
  short8 aqh1 = *(const short8*)(qh + qbase + 32 + kg * 8);
  short8 aql0 = *(const short8*)(ql + qbase + kg * 8);
  short8 aql1 = *(const short8*)(ql + qbase + 32 + kg * 8);

  floatx4 acc[4];
#pragma unroll
  for (int t = 0; t < 4; ++t)
#pragma unroll
    for (int r = 0; r < 4; ++r) acc[t][r] = 0.0f;
  float lsum[4] = {0.0f, 0.0f, 0.0f, 0.0f};

  short8 rkh[2], rkl[2], rvt[2];
#pragma unroll
  for (int it = 0; it < 2; ++it) {
    size_t gk = ((size_t)((b * L_ + it * 32 + srow) * H_ + h)) * DH_ + skoff;
    rkh[it] = *(const short8*)(kh + gk);
    rkl[it] = *(const short8*)(kl + gk);
    size_t gv = ((size_t)((b * H_ + h) * DH_ + it * 32 + srow)) * L_ + skoff;
    rvt[it] = *(const short8*)(vt + gv);
  }

  for (int c = 0; c < 16; ++c) {
    const int nb = c * 64;
    __syncthreads();               // previous chunk readers done
#pragma unroll
    for (int it = 0; it < 2; ++it) {
      *(short8*)&lKh[it * 32 + srow][skoff] = rkh[it];
      *(short8*)&lKl[it * 32 + srow][skoff] = rkl[it];
      *(short8*)&lVt[it * 32 + srow][skoff] = rvt[it];
    }
    __syncthreads();

    // bias (mask + shift) for this chunk -> MFMA C-init
    float bb[4][4];
#pragma unroll
    for (int r = 0; r < 4; ++r)
#pragma unroll
      for (int t = 0; t < 4; ++t)
        bb[r][t] = bias[(size_t)(qr0 + kg * 4 + r) * L_ + nb + t * 16 + m];

    // register prefetch of chunk c+1 (overlaps global latency with compute)
    if (c < 15) {
      const int nb2 = nb + 64;
#pragma unroll
      for (int it = 0; it < 2; ++it) {
        size_t gk = ((size_t)((b * L_ + nb2 + it * 32 + srow) * H_ + h)) * DH_ + skoff;
        rkh[it] = *(const short8*)(kh + gk);
        rkl[it] = *(const short8*)(kl + gk);
        size_t gv = ((size_t)((b * H_ + h) * DH_ + it * 32 + srow)) * L_ + nb2 + skoff;
        rvt[it] = *(const short8*)(vt + gv);
      }
    }

    // S = Q K^T + bias (3-term split emulation), bias as accumulator init
    floatx4 s[4];
#pragma unroll
    for (int t = 0; t < 4; ++t) {
      short8 kb0 = *(const short8*)&lKh[t * 16 + m][kg * 8];
      short8 kb1 = *(const short8*)&lKh[t * 16 + m][32 + kg * 8];
      short8 kx0 = *(const short8*)&lKl[t * 16 + m][kg * 8];
      short8 kx1 = *(const short8*)&lKl[t * 16 + m][32 + kg * 8];
      floatx4 z;
      z[0] = bb[0][t]; z[1] = bb[1][t]; z[2] = bb[2][t]; z[3] = bb[3][t];
      z = __builtin_amdgcn_mfma_f32_16x16x32_bf16(aqh0, kb0, z, 0, 0, 0);
      z = __builtin_amdgcn_mfma_f32_16x16x32_bf16(aqh1, kb1, z, 0, 0, 0);
      z = __builtin_amdgcn_mfma_f32_16x16x32_bf16(aqh0, kx0, z, 0, 0, 0);
      z = __builtin_amdgcn_mfma_f32_16x16x32_bf16(aqh1, kx1, z, 0, 0, 0);
      z = __builtin_amdgcn_mfma_f32_16x16x32_bf16(aql0, kb0, z, 0, 0, 0);
      z = __builtin_amdgcn_mfma_f32_16x16x32_bf16(aql1, kb1, z, 0, 0, 0);
      s[t] = z;
    }

    // fixed-shift softmax weights; P written permuted-contiguous (1 b64/row)
#pragma unroll
    for (int r = 0; r < 4; ++r) {
      float p0 = __expf(s[0][r]);
      float p1 = __expf(s[1][r]);
      float p2 = __expf(s[2][r]);
      float p3 = __expf(s[3][r]);
      lsum[r] += (p0 + p1) + (p2 + p3);
      uint2 pk;
      pk.x = pack_bf2(p0, p1);
      pk.y = pack_bf2(p2, p3);
      *(uint2*)&lP[w][kg * 4 + r][m * 4] = pk;   // pos m*4+t <-> key t*16+m
    }

    // O += P V (both in permuted key order; contraction order-invariant)
    short8 ap0 = *(const short8*)&lP[w][m][kg * 8];
    short8 ap1 = *(const short8*)&lP[w][m][32 + kg * 8];
#pragma unroll
    for (int t = 0; t < 4; ++t) {
      short8 b0 = *(const short8*)&lVt[t * 16 + m][kg * 8];
      short8 b1 = *(const short8*)&lVt[t * 16 + m][32 + kg * 8];
      acc[t] = __builtin_amdgcn_mfma_f32_16x16x32_bf16(ap0, b0, acc[t], 0, 0, 0);
      acc[t] = __builtin_amdgcn_mfma_f32_16x16x32_bf16(ap1, b1, acc[t], 0, 0, 0);
    }
  }

  // epilogue: one deferred sum reduction, normalize, split-store hi/lo
#pragma unroll
  for (int r = 0; r < 4; ++r) {
    float sm = lsum[r];
#pragma unroll
    for (int d = 1; d < 16; d <<= 1) sm += __shfl_xor(sm, d, 64);
    float inv = 1.0f / sm;
#pragma unroll
    for (int t = 0; t < 4; ++t) {
      float ov = acc[t][r] * inv;
      size_t idx = ((size_t)((b * L_ + qr0 + kg * 4 + r) * H_ + h)) * DH_ + t * 16 + m;
      u16 hh = f2bf(ov);
      ohi[idx] = hh;
      olo[idx] = f2bf(ov - bf2f(hh));
    }
  }
}

// ---------------------------------------------------------------- launch
extern "C" void kernel_launch(void* const* d_in, const int* in_sizes, int n_in,
                              void* d_out, int out_size, void* d_ws, size_t ws_size,
                              hipStream_t stream) {
  const float* x    = (const float*)d_in[0];
  const float* mask = (const float*)d_in[1];
  const float* Wk   = (const float*)d_in[2];
  const float* Wv   = (const float*)d_in[3];
  const float* Wq   = (const float*)d_in[4];
  const float* Wo   = (const float*)d_in[5];
  float* out = (float*)d_out;

  // ws (96 MB): xhi/xlo reused as attention-output hi/lo after projections.
  char* ws = (char*)d_ws;
  u16* xhi  = (u16*)(ws);                    // 16 MB ; later attn hi
  u16* xlo  = (u16*)(ws + (16ull << 20));    // 16 MB ; later attn lo
  u16* khi  = (u16*)(ws + (32ull << 20));
  u16* klo  = (u16*)(ws + (48ull << 20));
  u16* vtb  = (u16*)(ws + (64ull << 20));    // transposed+permuted V
  u16* wqh  = (u16*)(ws + (80ull << 20));
  u16* wql  = (u16*)(ws + (82ull << 20));
  u16* wkh  = (u16*)(ws + (84ull << 20));
  u16* wkl  = (u16*)(ws + (86ull << 20));
  u16* wvh  = (u16*)(ws + (88ull << 20));
  u16* woh  = (u16*)(ws + (90ull << 20));
  float* biasb = (float*)(ws + (92ull << 20));   // 4 MB -> 96 MB total
  // d_out (32 MB) timeline: vb (v proj) -> qhi/qlo -> final fp32 out
  u16* vb   = (u16*)d_out;
  u16* qhi  = (u16*)d_out;
  u16* qlo  = qhi + (size_t)B_ * L_ * D_;

  const int NX = B_ * L_ * D_;   // 8388608
  const int NW = D_ * D_;        // 1048576
  const int NM = L_ * L_;        // 1048576
  split_kernel<<<NX / 4 / 256, 256, 0, stream>>>(x,  xhi, xlo, NX);
  split_kernel<<<NW / 4 / 256, 256, 0, stream>>>(Wq, wqh, wql, NW);
  split_kernel<<<NW / 4 / 256, 256, 0, stream>>>(Wk, wkh, wkl, NW);
  cast_kernel <<<NW / 4 / 256, 256, 0, stream>>>(Wv, wvh, NW);
  cast_kernel <<<NW / 4 / 256, 256, 0, stream>>>(Wo, woh, NW);
  bias_kernel <<<NM / 4 / 256, 256, 0, stream>>>(mask, biasb, NM);

  dim3 gg(D_ / 128, (B_ * L_) / 128);   // (8, 64)
  // v first (into d_out), transpose, then q can overwrite vb's space
  gemm_bt<<<gg, 256, 0, stream>>>(xhi, wvh, vb, B_ * L_, D_, D_, 1.0f);
  dim3 gt(L_ / 64, B_ * H_);            // (16, 128)
  transpose_v<<<gt, 256, 0, stream>>>(vb, vtb);

  gemm_split<2, 3><<<gg, 256, 0, stream>>>(xhi, xlo, wqh, wql, qhi, qlo,
                                           B_ * L_, D_, D_, 0.125f);
  gemm_split<2, 3><<<gg, 256, 0, stream>>>(xhi, xlo, wkh, wkl, khi, klo,
                                           B_ * L_, D_, D_, 1.0f);

  dim3 ga(L_ / 64, B_ * H_);            // (16, 128)
  attn_kernel<<<ga, 256, 0, stream>>>(qhi, qlo, khi, klo, vtb, biasb, xhi, xlo);

  // final projection: 2-term (Ah+Al)·Wo_hi
  gemm_split<0, 2><<<gg, 256, 0, stream>>>(xhi, xlo, woh, woh, out, nullptr,
                                           B_ * L_, D_, D_, 1.0f);
}

// Round 5
// 314.735 us; speedup vs baseline: 1.8138x; 1.2896x over previous
//
#include <hip/hip_runtime.h>

// Problem constants (B=8, L=1024, D=1024, H=16, DH=64)
#define B_  8
#define L_  1024
#define D_  1024
#define H_  16
#define DH_ 64

typedef unsigned short u16;
typedef __attribute__((ext_vector_type(8))) short short8;      // 8 x bf16 (4 VGPRs)
typedef __attribute__((ext_vector_type(8))) _Float16 half8;    // 8 x f16  (4 VGPRs)
typedef __attribute__((ext_vector_type(4))) float floatx4;     // MFMA 16x16 C/D frag

// fp32 -> bf16 round-to-nearest-even
static __device__ __forceinline__ u16 f2bf(float f) {
  union { float f; unsigned u; } cv; cv.f = f;
  unsigned u = cv.u;
  return (u16)((u + 0x7fffu + ((u >> 16) & 1u)) >> 16);
}
// fp32 -> f16 bits (v_cvt_f16_f32, RNE)
static __device__ __forceinline__ u16 f2h(float f) {
  union { _Float16 h; u16 u; } cv; cv.h = (_Float16)f; return cv.u;
}
// pack two fp32 -> two bf16 (round-half-up; inputs are nonneg softmax weights)
static __device__ __forceinline__ unsigned pack_bf2(float a, float b) {
  union { float f; unsigned u; } ua, ub; ua.f = a; ub.f = b;
  return ((ua.u + 0x8000u) >> 16) | ((ub.u + 0x8000u) & 0xffff0000u);
}

// ---------------------------------------------------------------- f32 -> f16 cast
__global__ void cast16_kernel(const float* __restrict__ in, u16* __restrict__ out, int n) {
  int i = (blockIdx.x * blockDim.x + threadIdx.x) * 4;
  if (i + 4 > n) return;
  float4 f = *(const float4*)(in + i);
  ushort4 r;
  r.x = f2h(f.x); r.y = f2h(f.y); r.z = f2h(f.z); r.w = f2h(f.w);
  *(ushort4*)(out + i) = r;
}

// ---------------------------------------------------------------- permuted bias
// biasP float4[(((qt*4+w)*16+c)*64+lane)*4 + r] = {bias(row, col+t*16)}_t, where
// row = qt*64+w*16+(lane>>4)*4+r, col = c*64+(lane&15); bias = (mask-1)*1.25e8 - 24.
__global__ void bias_perm_kernel(const float* __restrict__ mask, float4* __restrict__ biasP) {
  int i = blockIdx.x * blockDim.x + threadIdx.x;      // 0 .. 262143 float4s
  int r    = i & 3;
  int lane = (i >> 2) & 63;
  int c    = (i >> 8) & 15;
  int w    = (i >> 12) & 3;
  int qt   = (i >> 14) & 15;
  int row  = qt * 64 + w * 16 + ((lane >> 4) << 2) + r;
  int colb = c * 64 + (lane & 15);
  float4 o;
  o.x = (mask[(size_t)row * L_ + colb +  0] - 1.0f) * 1.25e8f - 24.0f;
  o.y = (mask[(size_t)row * L_ + colb + 16] - 1.0f) * 1.25e8f - 24.0f;
  o.z = (mask[(size_t)row * L_ + colb + 32] - 1.0f) * 1.25e8f - 24.0f;
  o.w = (mask[(size_t)row * L_ + colb + 48] - 1.0f) * 1.25e8f - 24.0f;
  biasP[i] = o;
}

// ---------------------------------------------------------------- LDS staging helper
typedef __attribute__((address_space(3))) void  lds_void;
typedef const __attribute__((address_space(1))) void g_void;
static __device__ __forceinline__ void load_lds16(const void* g, void* l) {
  __builtin_amdgcn_global_load_lds((g_void*)g, (lds_void*)l, 16, 0, 0);
}

// ---------------------------------------------------------------- plain f16 GEMM (BT): C[m,n] = sum_k A[m,k]*B[n,k]
// OUT: 0 = f16, 1 = bf16, 2 = fp32
template <int OUT>
__global__ __launch_bounds__(256) void gemm_f16(const u16* __restrict__ A,
                                                const u16* __restrict__ Bw,
                                                void* __restrict__ Cp,
                                                int M, int N, int K, float scale) {
  __shared__ u16 lA[128 * 32];
  __shared__ u16 lB[128 * 32];
  const int tid  = threadIdx.x;
  const int w    = tid >> 6;
  const int lane = tid & 63;
  const int m    = lane & 15;
  const int kg   = lane >> 4;
  const int m0   = blockIdx.y * 128;
  const int n0   = blockIdx.x * 128;
  const int wm   = (w >> 1) * 64;
  const int wn   = (w & 1) * 64;
  const int rowS = tid >> 2;
  const int part = tid & 3;

  floatx4 acc[4][4];
#pragma unroll
  for (int i = 0; i < 4; ++i)
#pragma unroll
    for (int j = 0; j < 4; ++j)
#pragma unroll
      for (int r = 0; r < 4; ++r) acc[i][j][r] = 0.0f;

  for (int k0 = 0; k0 < K; k0 += 32) {
    __syncthreads();
#pragma unroll
    for (int rnd = 0; rnd < 2; ++rnd) {
      const u16* ga = A  + (size_t)(m0 + rnd * 64 + rowS) * K + k0 + part * 8;
      const u16* gb = Bw + (size_t)(n0 + rnd * 64 + rowS) * K + k0 + part * 8;
      load_lds16(ga, lA + rnd * 2048 + w * 512);
      load_lds16(gb, lB + rnd * 2048 + w * 512);
    }
    __syncthreads();

    half8 af[4], bf[4];
#pragma unroll
    for (int i = 0; i < 4; ++i) af[i] = *(const half8*)&lA[(wm + i * 16 + m) * 32 + kg * 8];
#pragma unroll
    for (int i = 0; i < 4; ++i) bf[i] = *(const half8*)&lB[(wn + i * 16 + m) * 32 + kg * 8];
#pragma unroll
    for (int mi = 0; mi < 4; ++mi)
#pragma unroll
      for (int ni = 0; ni < 4; ++ni)
        acc[mi][ni] = __builtin_amdgcn_mfma_f32_16x16x32_f16(af[mi], bf[ni], acc[mi][ni], 0, 0, 0);
  }

#pragma unroll
  for (int mi = 0; mi < 4; ++mi)
#pragma unroll
    for (int ni = 0; ni < 4; ++ni)
#pragma unroll
      for (int r = 0; r < 4; ++r) {
        int row = m0 + wm + mi * 16 + kg * 4 + r;
        int col = n0 + wn + ni * 16 + m;
        size_t idx = (size_t)row * N + col;
        float vv = acc[mi][ni][r] * scale;
        if (OUT == 0)      ((u16*)Cp)[idx]   = f2h(vv);
        else if (OUT == 1) ((u16*)Cp)[idx]   = f2bf(vv);
        else               ((float*)Cp)[idx] = vv;
      }
}

// ---------------------------------------------------------------- V transpose (+key permutation), bf16
// v (B,L,H,DH) -> vt[(b*H+h)*DH+dh][L], keys permuted within each 64-chunk:
// position p holds key l = ((p&3)<<4) + (p>>2)
__global__ __launch_bounds__(256) void transpose_v(const u16* __restrict__ v,
                                                   u16* __restrict__ vt) {
  __shared__ u16 lds[64][72];
  const int b  = blockIdx.y >> 4;
  const int h  = blockIdx.y & 15;
  const int l0 = blockIdx.x * 64;
  const int tid = threadIdx.x;
#pragma unroll
  for (int it = 0; it < 2; ++it) {
    int idx = it * 256 + tid;
    int i = idx >> 3, off = (idx & 7) * 8;
    *(short8*)&lds[i][off] =
        *(const short8*)(v + ((size_t)(b * L_ + l0 + i)) * D_ + h * 64 + off);
  }
  __syncthreads();
  const int j  = tid >> 2;
  const int p0 = (tid & 3) * 16;
  __attribute__((aligned(16))) u16 tmp[16];
#pragma unroll
  for (int s = 0; s < 16; ++s) {
    int p = p0 + s;
    int l = ((p & 3) << 4) + (p >> 2);
    tmp[s] = lds[l][j];
  }
  u16* dst = vt + ((size_t)((b * H_ + h) * DH_ + j)) * L_ + l0 + p0;
  *(short8*)(dst)     = *(const short8*)&tmp[0];
  *(short8*)(dst + 8) = *(const short8*)&tmp[8];
}

// ---------------------------------------------------------------- fused flash attention (f16 scores)
// grid (bh=128 fast for bias L2 reuse, qt=16). 4 waves x 16 q-rows.
// S = q_f16 · k_f16 + biasP (C-init). Fixed-shift softmax, deferred sum.
// P bf16 (range), V bf16 transposed+permuted. Output f16.
__global__ __launch_bounds__(256) void attn_kernel(const u16* __restrict__ q,
                                                   const u16* __restrict__ k,
                                                   const u16* __restrict__ vt,
                                                   const float4* __restrict__ biasP,
                                                   u16* __restrict__ o) {
  __shared__ u16 lK[64][72];       // f16 bits, [key][dh], stride 72
  __shared__ u16 lVt[64][72];      // bf16,     [dh][key-pos] (permuted)
  __shared__ u16 lP[4][16][72];    // bf16, wave-private, permuted-key layout

  const int bh   = blockIdx.x;     // fast dim -> same-qt blocks spread across XCDs
  const int qt   = blockIdx.y;
  const int b    = bh >> 4;
  const int h    = bh & 15;
  const int tid  = threadIdx.x;
  const int w    = tid >> 6;
  const int lane = tid & 63;
  const int m    = lane & 15;
  const int kg   = lane >> 4;
  const int qr0  = qt * 64 + w * 16;

  const int srow  = tid >> 3;        // 0..31 (+32 on second round)
  const int skoff = (tid & 7) * 8;

  // Q A-frags: A[m=lane&15][k=kg*8+j]
  const size_t qbase = ((size_t)((b * L_ + qr0 + m) * H_ + h)) * DH_;
  half8 aq0 = *(const half8*)(q + qbase + kg * 8);
  half8 aq1 = *(const half8*)(q + qbase + 32 + kg * 8);

  floatx4 acc[4];
#pragma unroll
  for (int t = 0; t < 4; ++t)
#pragma unroll
    for (int r = 0; r < 4; ++r) acc[t][r] = 0.0f;
  float lsum[4] = {0.0f, 0.0f, 0.0f, 0.0f};

  short8 rk[2], rv[2];
#pragma unroll
  for (int it = 0; it < 2; ++it) {
    size_t gk = ((size_t)((b * L_ + it * 32 + srow) * H_ + h)) * DH_ + skoff;
    rk[it] = *(const short8*)(k + gk);
    size_t gv = ((size_t)((b * H_ + h) * DH_ + it * 32 + srow)) * L_ + skoff;
    rv[it] = *(const short8*)(vt + gv);
  }

  const float4* bpw = biasP + ((size_t)(qt * 4 + w) * 16) * 256 + lane * 4;

  for (int c = 0; c < 16; ++c) {
    const int nb = c * 64;
    __syncthreads();               // previous chunk readers done
#pragma unroll
    for (int it = 0; it < 2; ++it) {
      *(short8*)&lK[it * 32 + srow][skoff]  = rk[it];
      *(short8*)&lVt[it * 32 + srow][skoff] = rv[it];
    }
    __syncthreads();

    // bias for this chunk (permuted layout: 4 x dwordx4)
    float bb[16];
    {
      const float4* bp = bpw + (size_t)c * 256;
      *(float4*)&bb[0]  = bp[0];
      *(float4*)&bb[4]  = bp[1];
      *(float4*)&bb[8]  = bp[2];
      *(float4*)&bb[12] = bp[3];
    }

    // register prefetch of chunk c+1
    if (c < 15) {
      const int nb2 = nb + 64;
#pragma unroll
      for (int it = 0; it < 2; ++it) {
        size_t gk = ((size_t)((b * L_ + nb2 + it * 32 + srow) * H_ + h)) * DH_ + skoff;
        rk[it] = *(const short8*)(k + gk);
        size_t gv = ((size_t)((b * H_ + h) * DH_ + it * 32 + srow)) * L_ + nb2 + skoff;
        rv[it] = *(const short8*)(vt + gv);
      }
    }

    // S = Q K^T + bias (f16 MFMA, bias as accumulator init)
    floatx4 s[4];
#pragma unroll
    for (int t = 0; t < 4; ++t) {
      half8 kb0 = *(const half8*)&lK[t * 16 + m][kg * 8];
      half8 kb1 = *(const half8*)&lK[t * 16 + m][32 + kg * 8];
      floatx4 z;
      z[0] = bb[0 * 4 + t]; z[1] = bb[1 * 4 + t]; z[2] = bb[2 * 4 + t]; z[3] = bb[3 * 4 + t];
      z = __builtin_amdgcn_mfma_f32_16x16x32_f16(aq0, kb0, z, 0, 0, 0);
      z = __builtin_amdgcn_mfma_f32_16x16x32_f16(aq1, kb1, z, 0, 0, 0);
      s[t] = z;
    }

    // fixed-shift softmax weights; P written permuted-contiguous (1 b64/row)
#pragma unroll
    for (int r = 0; r < 4; ++r) {
      float p0 = __expf(s[0][r]);
      float p1 = __expf(s[1][r]);
      float p2 = __expf(s[2][r]);
      float p3 = __expf(s[3][r]);
      lsum[r] += (p0 + p1) + (p2 + p3);
      uint2 pk;
      pk.x = pack_bf2(p0, p1);
      pk.y = pack_bf2(p2, p3);
      *(uint2*)&lP[w][kg * 4 + r][m * 4] = pk;   // pos m*4+t <-> key t*16+m
    }

    // O += P V (bf16 MFMA; both in permuted key order)
    short8 ap0 = *(const short8*)&lP[w][m][kg * 8];
    short8 ap1 = *(const short8*)&lP[w][m][32 + kg * 8];
#pragma unroll
    for (int t = 0; t < 4; ++t) {
      short8 b0 = *(const short8*)&lVt[t * 16 + m][kg * 8];
      short8 b1 = *(const short8*)&lVt[t * 16 + m][32 + kg * 8];
      acc[t] = __builtin_amdgcn_mfma_f32_16x16x32_bf16(ap0, b0, acc[t], 0, 0, 0);
      acc[t] = __builtin_amdgcn_mfma_f32_16x16x32_bf16(ap1, b1, acc[t], 0, 0, 0);
    }
  }

  // epilogue: one deferred sum reduction, normalize, store f16
#pragma unroll
  for (int r = 0; r < 4; ++r) {
    float sm = lsum[r];
#pragma unroll
    for (int d = 1; d < 16; d <<= 1) sm += __shfl_xor(sm, d, 64);
    float inv = 1.0f / sm;
#pragma unroll
    for (int t = 0; t < 4; ++t) {
      float ov = acc[t][r] * inv;
      size_t idx = ((size_t)((b * L_ + qr0 + kg * 4 + r) * H_ + h)) * DH_ + t * 16 + m;
      o[idx] = f2h(ov);
    }
  }
}

// ---------------------------------------------------------------- launch
extern "C" void kernel_launch(void* const* d_in, const int* in_sizes, int n_in,
                              void* d_out, int out_size, void* d_ws, size_t ws_size,
                              hipStream_t stream) {
  const float* x    = (const float*)d_in[0];
  const float* mask = (const float*)d_in[1];
  const float* Wk   = (const float*)d_in[2];
  const float* Wv   = (const float*)d_in[3];
  const float* Wq   = (const float*)d_in[4];
  const float* Wo   = (const float*)d_in[5];

  // ws (60 MB): xf slab reused as attention output after k-GEMM.
  char* ws = (char*)d_ws;
  u16* xf    = (u16*)(ws);                    // 16 MB x_f16 ; later attn out f16
  u16* aout  = xf;
  u16* kf    = (u16*)(ws + (16ull << 20));    // 16 MB k f16
  u16* vtb   = (u16*)(ws + (32ull << 20));    // 16 MB transposed+permuted V bf16
  float4* biasP = (float4*)(ws + (48ull << 20));  // 4 MB permuted bias
  u16* wqf   = (u16*)(ws + (52ull << 20));    // 2 MB each, f16 weights
  u16* wkf   = (u16*)(ws + (54ull << 20));
  u16* wvf   = (u16*)(ws + (56ull << 20));
  u16* wof   = (u16*)(ws + (58ull << 20));
  // d_out (32 MB) timeline: vb bf16 -> qf f16 -> final fp32 out
  u16* vb = (u16*)d_out;
  u16* qf = (u16*)d_out;

  const int NX = B_ * L_ * D_;   // 8388608
  const int NW = D_ * D_;        // 1048576
  cast16_kernel<<<NX / 4 / 256, 256, 0, stream>>>(x,  xf,  NX);
  cast16_kernel<<<NW / 4 / 256, 256, 0, stream>>>(Wq, wqf, NW);
  cast16_kernel<<<NW / 4 / 256, 256, 0, stream>>>(Wk, wkf, NW);
  cast16_kernel<<<NW / 4 / 256, 256, 0, stream>>>(Wv, wvf, NW);
  cast16_kernel<<<NW / 4 / 256, 256, 0, stream>>>(Wo, wof, NW);
  bias_perm_kernel<<<1024, 256, 0, stream>>>(mask, biasP);

  dim3 gg(D_ / 128, (B_ * L_) / 128);   // (8, 64)
  // v first (bf16, into d_out), transpose, then q overwrites that space
  gemm_f16<1><<<gg, 256, 0, stream>>>(xf, wvf, vb, B_ * L_, D_, D_, 1.0f);
  dim3 gt(L_ / 64, B_ * H_);            // (16, 128)
  transpose_v<<<gt, 256, 0, stream>>>(vb, vtb);

  gemm_f16<0><<<gg, 256, 0, stream>>>(xf, wqf, qf, B_ * L_, D_, D_, 0.125f);  // q pre-scaled
  gemm_f16<0><<<gg, 256, 0, stream>>>(xf, wkf, kf, B_ * L_, D_, D_, 1.0f);

  dim3 ga(B_ * H_, L_ / 64);            // (128, 16): bh fastest for bias L2 reuse
  attn_kernel<<<ga, 256, 0, stream>>>(qf, kf, vtb, biasP, aout);

  gemm_f16<2><<<gg, 256, 0, stream>>>(aout, wof, (float*)d_out, B_ * L_, D_, D_, 1.0f);
}

// Round 6
// 287.044 us; speedup vs baseline: 1.9888x; 1.0965x over previous
//
#include <hip/hip_runtime.h>

// Problem constants (B=8, L=1024, D=1024, H=16, DH=64)
#define B_  8
#define L_  1024
#define D_  1024
#define H_  16
#define DH_ 64

typedef unsigned short u16;
typedef __attribute__((ext_vector_type(8))) short short8;      // 8 x bf16
typedef __attribute__((ext_vector_type(8))) _Float16 half8;    // 8 x f16
typedef __attribute__((ext_vector_type(4))) float floatx4;     // 16x16 C/D frag
typedef __attribute__((ext_vector_type(16))) float floatx16;   // 32x32 C/D frag

// fp32 -> bf16 round-to-nearest-even
static __device__ __forceinline__ u16 f2bf(float f) {
  union { float f; unsigned u; } cv; cv.f = f;
  unsigned u = cv.u;
  return (u16)((u + 0x7fffu + ((u >> 16) & 1u)) >> 16);
}
// fp32 -> f16 (RNE)
static __device__ __forceinline__ u16 f2h(float f) {
  union { _Float16 h; u16 u; } cv; cv.h = (_Float16)f; return cv.u;
}
// pack two fp32 -> two bf16 (round-half-up; nonneg softmax weights) via v_perm
static __device__ __forceinline__ unsigned pack_bf2(float a, float b) {
  union { float f; unsigned u; } ua, ub; ua.f = a; ub.f = b;
  return __builtin_amdgcn_perm(ub.u + 0x8000u, ua.u + 0x8000u, 0x07060302u);
}

// ---------------------------------------------------------------- fused casts (x, Wq, Wk, Wv, Wo -> f16)
__global__ void cast_all(const float* __restrict__ x,  const float* __restrict__ wq,
                         const float* __restrict__ wk, const float* __restrict__ wv,
                         const float* __restrict__ wo,
                         u16* __restrict__ xf,  u16* __restrict__ wqf,
                         u16* __restrict__ wkf, u16* __restrict__ wvf,
                         u16* __restrict__ wof) {
  int blk = blockIdx.x;
  const float* src; u16* dst; int off;
  if (blk < 8192)       { src = x;  dst = xf;  off = blk; }
  else if (blk < 9216)  { src = wq; dst = wqf; off = blk - 8192; }
  else if (blk < 10240) { src = wk; dst = wkf; off = blk - 9216; }
  else if (blk < 11264) { src = wv; dst = wvf; off = blk - 10240; }
  else                  { src = wo; dst = wof; off = blk - 11264; }
  int i = off * 1024 + threadIdx.x * 4;
  float4 f = *(const float4*)(src + i);
  ushort4 r;
  r.x = f2h(f.x); r.y = f2h(f.y); r.z = f2h(f.z); r.w = f2h(f.w);
  *(ushort4*)(dst + i) = r;
}

// ---------------------------------------------------------------- permuted bias for 32x32 C-layout
// float index i: e=i&3, lane=(i>>2)&63, rr=(i>>8)&3, t=(i>>10)&1, c=(i>>11)&15,
// w=(i>>15)&3, qt=i>>17; reg=rr*4+e.
// row = qt*128 + w*32 + (reg&3)+8*(reg>>2)+4*(lane>>5); key = c*64 + t*32 + (lane&31)
__global__ void bias_perm_kernel(const float* __restrict__ mask, float* __restrict__ biasP) {
  int i = blockIdx.x * 256 + threadIdx.x;
  int e = i & 3, lane = (i >> 2) & 63, rr = (i >> 8) & 3, t = (i >> 10) & 1;
  int c = (i >> 11) & 15, w = (i >> 15) & 3, qt = i >> 17;
  int reg = rr * 4 + e;
  int row = qt * 128 + w * 32 + (reg & 3) + 8 * (reg >> 2) + 4 * (lane >> 5);
  int key = c * 64 + t * 32 + (lane & 31);
  biasP[i] = (mask[(size_t)row * L_ + key] - 1.0f) * 1.25e8f - 24.0f;
}

// ---------------------------------------------------------------- LDS staging helper
typedef __attribute__((address_space(3))) void  lds_void;
typedef const __attribute__((address_space(1))) void g_void;
static __device__ __forceinline__ void load_lds16(const void* g, void* l) {
  __builtin_amdgcn_global_load_lds((g_void*)g, (lds_void*)l, 16, 0, 0);
}

// ---------------------------------------------------------------- fused QKV GEMM (BT), f16 inputs
// grid (24, 64): n-blocks 0-7 -> q (scale 1/8, f16), 8-15 -> k (f16), 16-23 -> v (bf16)
__global__ __launch_bounds__(256) void gemm_qkv(const u16* __restrict__ A,
                                                const u16* __restrict__ wq,
                                                const u16* __restrict__ wk,
                                                const u16* __restrict__ wv,
                                                u16* __restrict__ qf,
                                                u16* __restrict__ kf,
                                                u16* __restrict__ vb) {
  const int K = D_, N = D_;
  int nb = blockIdx.x;
  const u16* Bw; u16* Cp; float scale; int obf;
  if (nb < 8)       { Bw = wq; Cp = qf; scale = 0.125f; obf = 0; }
  else if (nb < 16) { Bw = wk; Cp = kf; scale = 1.0f;   obf = 0; }
  else              { Bw = wv; Cp = vb; scale = 1.0f;   obf = 1; }
  const int n0 = (nb & 7) * 128;

  __shared__ u16 lA[128 * 32];
  __shared__ u16 lB[128 * 32];
  const int tid  = threadIdx.x;
  const int w    = tid >> 6;
  const int lane = tid & 63;
  const int m    = lane & 15;
  const int kg   = lane >> 4;
  const int m0   = blockIdx.y * 128;
  const int wm   = (w >> 1) * 64;
  const int wn   = (w & 1) * 64;
  const int rowS = tid >> 2;
  const int part = tid & 3;

  floatx4 acc[4][4];
#pragma unroll
  for (int i = 0; i < 4; ++i)
#pragma unroll
    for (int j = 0; j < 4; ++j)
#pragma unroll
      for (int r = 0; r < 4; ++r) acc[i][j][r] = 0.0f;

  for (int k0 = 0; k0 < K; k0 += 32) {
    __syncthreads();
#pragma unroll
    for (int rnd = 0; rnd < 2; ++rnd) {
      const u16* ga = A  + (size_t)(m0 + rnd * 64 + rowS) * K + k0 + part * 8;
      const u16* gb = Bw + (size_t)(n0 + rnd * 64 + rowS) * K + k0 + part * 8;
      load_lds16(ga, lA + rnd * 2048 + w * 512);
      load_lds16(gb, lB + rnd * 2048 + w * 512);
    }
    __syncthreads();

    half8 af[4], bf[4];
#pragma unroll
    for (int i = 0; i < 4; ++i) af[i] = *(const half8*)&lA[(wm + i * 16 + m) * 32 + kg * 8];
#pragma unroll
    for (int i = 0; i < 4; ++i) bf[i] = *(const half8*)&lB[(wn + i * 16 + m) * 32 + kg * 8];
#pragma unroll
    for (int mi = 0; mi < 4; ++mi)
#pragma unroll
      for (int ni = 0; ni < 4; ++ni)
        acc[mi][ni] = __builtin_amdgcn_mfma_f32_16x16x32_f16(af[mi], bf[ni], acc[mi][ni], 0, 0, 0);
  }

#pragma unroll
  for (int mi = 0; mi < 4; ++mi)
#pragma unroll
    for (int ni = 0; ni < 4; ++ni)
#pragma unroll
      for (int r = 0; r < 4; ++r) {
        int row = m0 + wm + mi * 16 + kg * 4 + r;
        int col = n0 + wn + ni * 16 + m;
        size_t idx = (size_t)row * N + col;
        float vv = acc[mi][ni][r] * scale;
        Cp[idx] = obf ? f2bf(vv) : f2h(vv);
      }
}

// ---------------------------------------------------------------- final GEMM (BT), f16 in, fp32 out
__global__ __launch_bounds__(256) void gemm_fin(const u16* __restrict__ A,
                                                const u16* __restrict__ Bw,
                                                float* __restrict__ Cp,
                                                int M, int N, int K) {
  __shared__ u16 lA[128 * 32];
  __shared__ u16 lB[128 * 32];
  const int tid  = threadIdx.x;
  const int w    = tid >> 6;
  const int lane = tid & 63;
  const int m    = lane & 15;
  const int kg   = lane >> 4;
  const int m0   = blockIdx.y * 128;
  const int n0   = blockIdx.x * 128;
  const int wm   = (w >> 1) * 64;
  const int wn   = (w & 1) * 64;
  const int rowS = tid >> 2;
  const int part = tid & 3;

  floatx4 acc[4][4];
#pragma unroll
  for (int i = 0; i < 4; ++i)
#pragma unroll
    for (int j = 0; j < 4; ++j)
#pragma unroll
      for (int r = 0; r < 4; ++r) acc[i][j][r] = 0.0f;

  for (int k0 = 0; k0 < K; k0 += 32) {
    __syncthreads();
#pragma unroll
    for (int rnd = 0; rnd < 2; ++rnd) {
      const u16* ga = A  + (size_t)(m0 + rnd * 64 + rowS) * K + k0 + part * 8;
      const u16* gb = Bw + (size_t)(n0 + rnd * 64 + rowS) * K + k0 + part * 8;
      load_lds16(ga, lA + rnd * 2048 + w * 512);
      load_lds16(gb, lB + rnd * 2048 + w * 512);
    }
    __syncthreads();

    half8 af[4], bf[4];
#pragma unroll
    for (int i = 0; i < 4; ++i) af[i] = *(const half8*)&lA[(wm + i * 16 + m) * 32 + kg * 8];
#pragma unroll
    for (int i = 0; i < 4; ++i) bf[i] = *(const half8*)&lB[(wn + i * 16 + m) * 32 + kg * 8];
#pragma unroll
    for (int mi = 0; mi < 4; ++mi)
#pragma unroll
      for (int ni = 0; ni < 4; ++ni)
        acc[mi][ni] = __builtin_amdgcn_mfma_f32_16x16x32_f16(af[mi], bf[ni], acc[mi][ni], 0, 0, 0);
  }

#pragma unroll
  for (int mi = 0; mi < 4; ++mi)
#pragma unroll
    for (int ni = 0; ni < 4; ++ni)
#pragma unroll
      for (int r = 0; r < 4; ++r) {
        int row = m0 + wm + mi * 16 + kg * 4 + r;
        int col = n0 + wn + ni * 16 + m;
        Cp[(size_t)row * N + col] = acc[mi][ni][r];
      }
}

// ---------------------------------------------------------------- V transpose (+key permutation), bf16
// v (B,L,H,DH) -> vt[(b*H+h)*DH+dh][L]; within each 64-chunk, position p holds
// key l = (p>>1) + ((p&1)<<5)   (inverse of: key kt*32+c -> pos c*2+kt)
__global__ __launch_bounds__(256) void transpose_v(const u16* __restrict__ v,
                                                   u16* __restrict__ vt) {
  __shared__ u16 lds[64][72];
  const int b  = blockIdx.y >> 4;
  const int h  = blockIdx.y & 15;
  const int l0 = blockIdx.x * 64;
  const int tid = threadIdx.x;
#pragma unroll
  for (int it = 0; it < 2; ++it) {
    int idx = it * 256 + tid;
    int i = idx >> 3, off = (idx & 7) * 8;
    *(short8*)&lds[i][off] =
        *(const short8*)(v + ((size_t)(b * L_ + l0 + i)) * D_ + h * 64 + off);
  }
  __syncthreads();
  const int j  = tid >> 2;          // dh
  const int p0 = (tid & 3) * 16;
  __attribute__((aligned(16))) u16 tmp[16];
#pragma unroll
  for (int s = 0; s < 16; ++s) {
    int p = p0 + s;
    int l = (p >> 1) + ((p & 1) << 5);
    tmp[s] = lds[l][j];
  }
  u16* dst = vt + ((size_t)((b * H_ + h) * DH_ + j)) * L_ + l0 + p0;
  *(short8*)(dst)     = *(const short8*)&tmp[0];
  *(short8*)(dst + 8) = *(const short8*)&tmp[8];
}

// ---------------------------------------------------------------- fused flash attention, 32x32 MFMA
// grid (bh=128, qt=8). 4 waves x 32 q-rows = 128 rows/block. 64-key chunks.
// S: mfma_f32_32x32x16_f16 (bias C-init, fixed-shift softmax). P bf16 in
// tile-paired permuted layout (pos = c*2+kt). PV + rowsum via bf16 32x32 MFMAs.
__global__ __launch_bounds__(256) void attn_kernel(const u16* __restrict__ q,
                                                   const u16* __restrict__ k,
                                                   const u16* __restrict__ vt,
                                                   const float* __restrict__ biasP,
                                                   u16* __restrict__ o) {
  __shared__ u16 lK[64][72];       // f16, [key][dh]
  __shared__ u16 lVt[64][72];      // bf16, [dh][pos] (permuted keys)
  __shared__ u16 lP[4][32][72];    // bf16, wave-private, [q-row][pos]

  const int bh = blockIdx.x, qt = blockIdx.y;
  const int b = bh >> 4, h = bh & 15;
  const int tid = threadIdx.x;
  const int w = tid >> 6, lane = tid & 63;
  const int c32 = lane & 31, hi = lane >> 5;
  const int qr0 = qt * 128 + w * 32;

  const int srow  = tid >> 3;      // 0..31 (+32 second round)
  const int skoff = (tid & 7) * 8;

  // Q A-frags: A[m=lane&31][k-slot], 4 dh-slices
  const size_t qbase = ((size_t)((b * L_ + qr0 + c32) * H_ + h)) * DH_;
  half8 aq[4];
#pragma unroll
  for (int ks = 0; ks < 4; ++ks)
    aq[ks] = *(const half8*)(q + qbase + ks * 16 + hi * 8);

  floatx16 acc0, acc1, sumacc;
#pragma unroll
  for (int i = 0; i < 16; ++i) { acc0[i] = 0.0f; acc1[i] = 0.0f; sumacc[i] = 0.0f; }

  short8 ones;                     // bf16 1.0 per element
#pragma unroll
  for (int j = 0; j < 8; ++j) ones[j] = (short)0x3F80;

  short8 rk[2], rv[2];             // chunk-0 prefetch
#pragma unroll
  for (int it = 0; it < 2; ++it) {
    rk[it] = *(const short8*)(k + ((size_t)((b * L_ + it * 32 + srow) * H_ + h)) * DH_ + skoff);
    rv[it] = *(const short8*)(vt + ((size_t)((b * H_ + h) * DH_ + it * 32 + srow)) * L_ + skoff);
  }

  const float4* bias4 = (const float4*)(biasP + ((size_t)(qt * 4 + w) * 16) * 2048) + lane;

  for (int c = 0; c < 16; ++c) {
    __syncthreads();               // previous chunk readers done
#pragma unroll
    for (int it = 0; it < 2; ++it) {
      *(short8*)&lK[it * 32 + srow][skoff]  = rk[it];
      *(short8*)&lVt[it * 32 + srow][skoff] = rv[it];
    }
    __syncthreads();

    if (c < 15) {                  // register prefetch of chunk c+1
      const int nb2 = (c + 1) * 64;
#pragma unroll
      for (int it = 0; it < 2; ++it) {
        rk[it] = *(const short8*)(k + ((size_t)((b * L_ + nb2 + it * 32 + srow) * H_ + h)) * DH_ + skoff);
        rv[it] = *(const short8*)(vt + ((size_t)((b * H_ + h) * DH_ + it * 32 + srow)) * L_ + nb2 + skoff);
      }
    }

    // S tiles (2 key-tiles of 32), bias as accumulator init
    const float4* bp = bias4 + (size_t)c * 512;
    floatx16 s0, s1;
#pragma unroll
    for (int rr = 0; rr < 4; ++rr) {
      float4 b0 = bp[rr * 64];
      float4 b1 = bp[(4 + rr) * 64];
      s0[rr * 4 + 0] = b0.x; s0[rr * 4 + 1] = b0.y; s0[rr * 4 + 2] = b0.z; s0[rr * 4 + 3] = b0.w;
      s1[rr * 4 + 0] = b1.x; s1[rr * 4 + 1] = b1.y; s1[rr * 4 + 2] = b1.z; s1[rr * 4 + 3] = b1.w;
    }
#pragma unroll
    for (int ks = 0; ks < 4; ++ks) {
      half8 bk0 = *(const half8*)&lK[c32][ks * 16 + hi * 8];
      half8 bk1 = *(const half8*)&lK[32 + c32][ks * 16 + hi * 8];
      s0 = __builtin_amdgcn_mfma_f32_32x32x16_f16(aq[ks], bk0, s0, 0, 0, 0);
      s1 = __builtin_amdgcn_mfma_f32_32x32x16_f16(aq[ks], bk1, s1, 0, 0, 0);
    }

    // fixed-shift softmax weights; tile-paired b32 writes (pos = c32*2 + kt)
#pragma unroll
    for (int reg = 0; reg < 16; ++reg) {
      float p0 = __expf(s0[reg]);
      float p1 = __expf(s1[reg]);
      int row = (reg & 3) + 8 * (reg >> 2) + 4 * hi;
      *(unsigned*)&lP[w][row][c32 * 2] = pack_bf2(p0, p1);
    }

    // O += P V (2 dh-tiles) and rowsum += P . ones
#pragma unroll
    for (int ks = 0; ks < 4; ++ks) {
      short8 ap  = *(const short8*)&lP[w][c32][ks * 16 + hi * 8];
      short8 bv0 = *(const short8*)&lVt[c32][ks * 16 + hi * 8];
      short8 bv1 = *(const short8*)&lVt[32 + c32][ks * 16 + hi * 8];
      acc0   = __builtin_amdgcn_mfma_f32_32x32x16_bf16(ap, bv0, acc0, 0, 0, 0);
      acc1   = __builtin_amdgcn_mfma_f32_32x32x16_bf16(ap, bv1, acc1, 0, 0, 0);
      sumacc = __builtin_amdgcn_mfma_f32_32x32x16_bf16(ap, ones, sumacc, 0, 0, 0);
    }
  }

  // epilogue: normalize by rowsum (C-layout: reg <-> row, cols all equal), store f16
#pragma unroll
  for (int reg = 0; reg < 16; ++reg) {
    int row = qr0 + (reg & 3) + 8 * (reg >> 2) + 4 * hi;
    float inv = 1.0f / sumacc[reg];
    size_t obase = ((size_t)((b * L_ + row) * H_ + h)) * DH_;
    o[obase + c32]      = f2h(acc0[reg] * inv);
    o[obase + 32 + c32] = f2h(acc1[reg] * inv);
  }
}

// ---------------------------------------------------------------- launch
extern "C" void kernel_launch(void* const* d_in, const int* in_sizes, int n_in,
                              void* d_out, int out_size, void* d_ws, size_t ws_size,
                              hipStream_t stream) {
  const float* x    = (const float*)d_in[0];
  const float* mask = (const float*)d_in[1];
  const float* Wk   = (const float*)d_in[2];
  const float* Wv   = (const float*)d_in[3];
  const float* Wq   = (const float*)d_in[4];
  const float* Wo   = (const float*)d_in[5];

  // ws (60 MB): xf reused as attention output after qkv GEMM.
  char* ws = (char*)d_ws;
  u16* xf    = (u16*)(ws);                        // 16 MB x f16 ; later attn out f16
  u16* aout  = xf;
  u16* kf    = (u16*)(ws + (16ull << 20));        // 16 MB k f16
  u16* vtb   = (u16*)(ws + (32ull << 20));        // 16 MB transposed+permuted V bf16
  float* biasP = (float*)(ws + (48ull << 20));    // 4 MB permuted bias
  u16* wqf   = (u16*)(ws + (52ull << 20));        // 2 MB each, f16 weights
  u16* wkf   = (u16*)(ws + (54ull << 20));
  u16* wvf   = (u16*)(ws + (56ull << 20));
  u16* wof   = (u16*)(ws + (58ull << 20));
  // d_out (32 MB): qf (lower 16) + vb (upper 16) -> final fp32 out overwrites
  u16* qf = (u16*)d_out;
  u16* vb = qf + (size_t)B_ * L_ * D_;

  cast_all<<<12288, 256, 0, stream>>>(x, Wq, Wk, Wv, Wo, xf, wqf, wkf, wvf, wof);
  bias_perm_kernel<<<4096, 256, 0, stream>>>(mask, biasP);

  gemm_qkv<<<dim3(24, 64), 256, 0, stream>>>(xf, wqf, wkf, wvf, qf, kf, vb);

  transpose_v<<<dim3(L_ / 64, B_ * H_), 256, 0, stream>>>(vb, vtb);

  attn_kernel<<<dim3(B_ * H_, L_ / 128), 256, 0, stream>>>(qf, kf, vtb, biasP, aout);

  gemm_fin<<<dim3(D_ / 128, (B_ * L_) / 128), 256, 0, stream>>>(
      aout, wof, (float*)d_out, B_ * L_, D_, D_);
}